// Round 1
// baseline (625.983 us; speedup 1.0000x reference)
//
#include <hip/hip_runtime.h>

#define DIM 128

// ---------------- degree / CSR build ----------------

__global__ __launch_bounds__(256) void k_deg_init(int* __restrict__ deg, int N) {
    int i = blockIdx.x * 256 + threadIdx.x;
    if (i < N) deg[i] = 1;  // self-loop
}

__global__ __launch_bounds__(256) void k_count(const int* __restrict__ ei, int* __restrict__ deg,
                                               int E) {
    int e = blockIdx.x * 256 + threadIdx.x;
    if (e < E) {
        int dst = ei[E + e];
        atomicAdd(&deg[dst], 1);
    }
}

__global__ __launch_bounds__(256) void k_dinv(const int* __restrict__ deg, float* __restrict__ dinv,
                                              int N) {
    int i = blockIdx.x * 256 + threadIdx.x;
    if (i < N) dinv[i] = rsqrtf((float)deg[i]);
}

// hierarchical exclusive scan of (deg[i]-1) -> row_ptr
__global__ __launch_bounds__(256) void k_scanA(const int* __restrict__ deg, int* __restrict__ tmp,
                                               int* __restrict__ bsum, int N) {
    __shared__ int s[256];
    int tid = threadIdx.x;
    int i = blockIdx.x * 256 + tid;
    int v = (i < N) ? (deg[i] - 1) : 0;
    s[tid] = v;
    __syncthreads();
    for (int off = 1; off < 256; off <<= 1) {
        int t = (tid >= off) ? s[tid - off] : 0;
        __syncthreads();
        s[tid] += t;
        __syncthreads();
    }
    if (i < N) tmp[i] = s[tid];  // inclusive within block
    if (tid == 255) bsum[blockIdx.x] = s[255];
}

__global__ __launch_bounds__(1024) void k_scanB(int* __restrict__ bsum, int nb) {
    __shared__ int s[1024];
    int tid = threadIdx.x;
    int v = (tid < nb) ? bsum[tid] : 0;
    s[tid] = v;
    __syncthreads();
    for (int off = 1; off < 1024; off <<= 1) {
        int t = (tid >= off) ? s[tid - off] : 0;
        __syncthreads();
        s[tid] += t;
        __syncthreads();
    }
    if (tid < nb) bsum[tid] = s[tid] - v;  // exclusive block offsets
}

__global__ __launch_bounds__(256) void k_scanC(const int* __restrict__ deg,
                                               const int* __restrict__ tmp,
                                               const int* __restrict__ bsum, int* __restrict__ rp,
                                               int* __restrict__ fp, int N, int E) {
    int i = blockIdx.x * 256 + threadIdx.x;
    if (i < N) {
        int excl = bsum[blockIdx.x] + tmp[i] - (deg[i] - 1);
        rp[i] = excl;
        fp[i] = excl;
    }
    if (i == 0) rp[N] = E;
}

__global__ __launch_bounds__(256) void k_fill(const int* __restrict__ ei, int* __restrict__ fp,
                                              int* __restrict__ col, int E) {
    int e = blockIdx.x * 256 + threadIdx.x;
    if (e < E) {
        int src = ei[e];
        int dst = ei[E + e];
        int p = atomicAdd(&fp[dst], 1);
        col[p] = src;
    }
}

// ---------------- LayerNorm (+ pre-scale by dinv) ----------------

__global__ __launch_bounds__(256) void k_ln(const float* __restrict__ x,
                                            const float* __restrict__ w,
                                            const float* __restrict__ bb,
                                            const float* __restrict__ dinv, float* __restrict__ u,
                                            int N) {
    int row = (blockIdx.x * 256 + threadIdx.x) >> 6;
    int lane = threadIdx.x & 63;
    if (row >= N) return;
    float2 v = *(const float2*)(x + (size_t)row * DIM + lane * 2);
    float s = v.x + v.y;
#pragma unroll
    for (int o = 32; o; o >>= 1) s += __shfl_xor(s, o, 64);
    float mu = s * (1.0f / 128.0f);
    float dx0 = v.x - mu, dx1 = v.y - mu;
    float ss = dx0 * dx0 + dx1 * dx1;
#pragma unroll
    for (int o = 32; o; o >>= 1) ss += __shfl_xor(ss, o, 64);
    float rs = rsqrtf(ss * (1.0f / 128.0f) + 1e-5f);
    float2 wv = *(const float2*)(w + lane * 2);
    float2 bv = *(const float2*)(bb + lane * 2);
    float di = dinv[row];
    float2 o_;
    o_.x = (dx0 * rs * wv.x + bv.x) * di;
    o_.y = (dx1 * rs * wv.y + bv.y) * di;
    *(float2*)(u + (size_t)row * DIM + lane * 2) = o_;
}

// ---------------- propagate: Y[i] = scale * (X[i] + sum_{e in(i)} X[src]) ----------------

__global__ __launch_bounds__(256) void k_prop(const float* __restrict__ X, float* __restrict__ Y,
                                              const int* __restrict__ rp,
                                              const int* __restrict__ col,
                                              const float* __restrict__ dinv, int N, int squared) {
    int node = (blockIdx.x * 256 + threadIdx.x) >> 6;
    int lane = threadIdx.x & 63;
    if (node >= N) return;
    int e0 = rp[node], e1 = rp[node + 1];
    float2 acc = *(const float2*)(X + (size_t)node * DIM + lane * 2);
    for (int e = e0; e < e1; ++e) {
        int s = col[e];
        float2 g = *(const float2*)(X + (size_t)s * DIM + lane * 2);
        acc.x += g.x;
        acc.y += g.y;
    }
    float di = dinv[node];
    float sc = squared ? di * di : di;
    acc.x *= sc;
    acc.y *= sc;
    *(float2*)(Y + (size_t)node * DIM + lane * 2) = acc;
}

// ---------------- W transpose + tall-skinny matmul ----------------

__global__ __launch_bounds__(256) void k_transW(const float* __restrict__ W,
                                                float* __restrict__ Wt) {
    int i = blockIdx.x * 256 + threadIdx.x;  // 16384
    int o = i >> 7, d = i & 127;
    Wt[d * DIM + o] = W[i];
}

#define ZS_STRIDE 132  // 128 + 4 pad: 16B-aligned rows, bank-spread

__global__ __launch_bounds__(256) void k_matmul(const float* __restrict__ Z,
                                                const float* __restrict__ Wt,
                                                const float* __restrict__ b,
                                                float* __restrict__ out, int N) {
    __shared__ float Zs[64 * ZS_STRIDE];
    int tid = threadIdx.x;
    int rowBase = blockIdx.x * 64;
    // stage 64 rows of Z into LDS (coalesced float4)
    for (int t = tid; t < 64 * 32; t += 256) {
        int r = t >> 5, c4 = (t & 31) << 2;
        int g = rowBase + r;
        float4 v = make_float4(0.f, 0.f, 0.f, 0.f);
        if (g < N) v = *(const float4*)(Z + (size_t)g * DIM + c4);
        *(float4*)(&Zs[r * ZS_STRIDE + c4]) = v;
    }
    __syncthreads();
    int ridx = tid >> 5;   // 0..7  -> rows ridx*8 .. ridx*8+7
    int cidx = tid & 31;   // 0..31 -> cols cidx*4 .. cidx*4+3
    int ob = cidx << 2;
    float acc[8][4];
#pragma unroll
    for (int j = 0; j < 8; j++)
#pragma unroll
        for (int c = 0; c < 4; c++) acc[j][c] = 0.f;
    const float* zrow = &Zs[(ridx * 8) * ZS_STRIDE];
#pragma unroll 2
    for (int d = 0; d < 128; d += 4) {
        float4 w0 = *(const float4*)(Wt + (d + 0) * DIM + ob);
        float4 w1 = *(const float4*)(Wt + (d + 1) * DIM + ob);
        float4 w2 = *(const float4*)(Wt + (d + 2) * DIM + ob);
        float4 w3 = *(const float4*)(Wt + (d + 3) * DIM + ob);
#pragma unroll
        for (int j = 0; j < 8; j++) {
            float4 z = *(const float4*)(&zrow[j * ZS_STRIDE + d]);
            acc[j][0] += z.x * w0.x + z.y * w1.x + z.z * w2.x + z.w * w3.x;
            acc[j][1] += z.x * w0.y + z.y * w1.y + z.z * w2.y + z.w * w3.y;
            acc[j][2] += z.x * w0.z + z.y * w1.z + z.z * w2.z + z.w * w3.z;
            acc[j][3] += z.x * w0.w + z.y * w1.w + z.z * w2.w + z.w * w3.w;
        }
    }
    float4 bv = *(const float4*)(b + ob);
#pragma unroll
    for (int j = 0; j < 8; j++) {
        int g = rowBase + ridx * 8 + j;
        if (g < N) {
            float4 o_;
            o_.x = acc[j][0] + bv.x;
            o_.y = acc[j][1] + bv.y;
            o_.z = acc[j][2] + bv.z;
            o_.w = acc[j][3] + bv.w;
            *(float4*)(out + (size_t)g * DIM + ob) = o_;
        }
    }
}

// ---------------- launch ----------------

extern "C" void kernel_launch(void* const* d_in, const int* in_sizes, int n_in, void* d_out,
                              int out_size, void* d_ws, size_t ws_size, hipStream_t stream) {
    const float* x = (const float*)d_in[0];
    const int* ei = (const int*)d_in[1];
    const float* ln_w = (const float*)d_in[2];
    const float* ln_b = (const float*)d_in[3];
    const float* W = (const float*)d_in[4];
    const float* b = (const float*)d_in[5];
    float* out = (float*)d_out;

    int N = in_sizes[0] / DIM;
    int E = in_sizes[1] / 2;

    // workspace carve-up (all 256B-aligned)
    char* p = (char*)d_ws;
    auto carve = [&](size_t bytes) {
        void* r = (void*)p;
        p += (bytes + 255) & ~(size_t)255;
        return r;
    };
    float* u = (float*)carve((size_t)N * DIM * 4);   // 51.2 MB ping buffer
    float* Wt = (float*)carve(DIM * DIM * 4);        // 64 KB
    int* deg = (int*)carve((size_t)N * 4);
    float* dinv = (float*)carve((size_t)N * 4);
    int* rp = (int*)carve((size_t)(N + 1) * 4);
    int* fp = (int*)carve((size_t)N * 4);
    int* tmp = (int*)carve((size_t)N * 4);
    int* bsum = (int*)carve(1024 * 4);
    int* col = (int*)carve((size_t)E * 4);           // 6.4 MB

    int gN = (N + 255) / 256;   // 391
    int gE = (E + 255) / 256;   // 6250
    int gW = (N + 3) / 4;       // wave-per-row kernels: 25000
    int gM = (N + 63) / 64;     // matmul row blocks: 1563

    k_deg_init<<<gN, 256, 0, stream>>>(deg, N);
    k_count<<<gE, 256, 0, stream>>>(ei, deg, E);
    k_dinv<<<gN, 256, 0, stream>>>(deg, dinv, N);
    k_scanA<<<gN, 256, 0, stream>>>(deg, tmp, bsum, N);
    k_scanB<<<1, 1024, 0, stream>>>(bsum, gN);
    k_scanC<<<gN, 256, 0, stream>>>(deg, tmp, bsum, rp, fp, N, E);
    k_fill<<<gE, 256, 0, stream>>>(ei, fp, col, E);
    k_transW<<<64, 256, 0, stream>>>(W, Wt);
    k_ln<<<gW, 256, 0, stream>>>(x, ln_w, ln_b, dinv, u, N);
    // hop 1: u -> d_out (as u1, pre-scaled by dinv^2 for next hop)
    k_prop<<<gW, 256, 0, stream>>>(u, out, rp, col, dinv, N, 1);
    // hop 2: d_out -> u (final z2, scaled by dinv)
    k_prop<<<gW, 256, 0, stream>>>(out, u, rp, col, dinv, N, 0);
    // out = z2 @ W^T + b (reads u, writes d_out)
    k_matmul<<<gM, 256, 0, stream>>>(u, Wt, b, out, N);
}

// Round 2
// 477.420 us; speedup vs baseline: 1.3112x; 1.3112x over previous
//
#include <hip/hip_runtime.h>
#include <hip/hip_fp16.h>

#define DIM 128

// ---------------- degree / CSR build ----------------

__global__ __launch_bounds__(256) void k_deg_init(int* __restrict__ deg, int N) {
    int i = blockIdx.x * 256 + threadIdx.x;
    if (i < N) deg[i] = 1;  // self-loop
}

__global__ __launch_bounds__(256) void k_count(const int* __restrict__ ei, int* __restrict__ deg,
                                               int E) {
    int e = blockIdx.x * 256 + threadIdx.x;
    if (e < E) {
        int dst = ei[E + e];
        atomicAdd(&deg[dst], 1);
    }
}

__global__ __launch_bounds__(256) void k_dinv(const int* __restrict__ deg, float* __restrict__ dinv,
                                              int N) {
    int i = blockIdx.x * 256 + threadIdx.x;
    if (i < N) dinv[i] = rsqrtf((float)deg[i]);
}

// hierarchical exclusive scan of (deg[i]-1) -> row_ptr
__global__ __launch_bounds__(256) void k_scanA(const int* __restrict__ deg, int* __restrict__ tmp,
                                               int* __restrict__ bsum, int N) {
    __shared__ int s[256];
    int tid = threadIdx.x;
    int i = blockIdx.x * 256 + tid;
    int v = (i < N) ? (deg[i] - 1) : 0;
    s[tid] = v;
    __syncthreads();
    for (int off = 1; off < 256; off <<= 1) {
        int t = (tid >= off) ? s[tid - off] : 0;
        __syncthreads();
        s[tid] += t;
        __syncthreads();
    }
    if (i < N) tmp[i] = s[tid];  // inclusive within block
    if (tid == 255) bsum[blockIdx.x] = s[255];
}

__global__ __launch_bounds__(1024) void k_scanB(int* __restrict__ bsum, int nb) {
    __shared__ int s[1024];
    int tid = threadIdx.x;
    int v = (tid < nb) ? bsum[tid] : 0;
    s[tid] = v;
    __syncthreads();
    for (int off = 1; off < 1024; off <<= 1) {
        int t = (tid >= off) ? s[tid - off] : 0;
        __syncthreads();
        s[tid] += t;
        __syncthreads();
    }
    if (tid < nb) bsum[tid] = s[tid] - v;  // exclusive block offsets
}

__global__ __launch_bounds__(256) void k_scanC(const int* __restrict__ deg,
                                               const int* __restrict__ tmp,
                                               const int* __restrict__ bsum, int* __restrict__ rp,
                                               int* __restrict__ fp, int N, int E) {
    int i = blockIdx.x * 256 + threadIdx.x;
    if (i < N) {
        int excl = bsum[blockIdx.x] + tmp[i] - (deg[i] - 1);
        rp[i] = excl;
        fp[i] = excl;
    }
    if (i == 0) rp[N] = E;
}

__global__ __launch_bounds__(256) void k_fill(const int* __restrict__ ei, int* __restrict__ fp,
                                              int* __restrict__ col, int E) {
    int e = blockIdx.x * 256 + threadIdx.x;
    if (e < E) {
        int src = ei[e];
        int dst = ei[E + e];
        int p = atomicAdd(&fp[dst], 1);
        col[p] = src;
    }
}

// ---------------- LayerNorm (+ pre-scale by dinv), fp16 output ----------------

__global__ __launch_bounds__(256) void k_ln(const float* __restrict__ x,
                                            const float* __restrict__ w,
                                            const float* __restrict__ bb,
                                            const float* __restrict__ dinv,
                                            __half2* __restrict__ u, int N) {
    int row = (blockIdx.x * 256 + threadIdx.x) >> 6;
    int lane = threadIdx.x & 63;
    if (row >= N) return;
    float2 v = *(const float2*)(x + (size_t)row * DIM + lane * 2);
    float s = v.x + v.y;
#pragma unroll
    for (int o = 32; o; o >>= 1) s += __shfl_xor(s, o, 64);
    float mu = s * (1.0f / 128.0f);
    float dx0 = v.x - mu, dx1 = v.y - mu;
    float ss = dx0 * dx0 + dx1 * dx1;
#pragma unroll
    for (int o = 32; o; o >>= 1) ss += __shfl_xor(ss, o, 64);
    float rs = rsqrtf(ss * (1.0f / 128.0f) + 1e-5f);
    float2 wv = *(const float2*)(w + lane * 2);
    float2 bv = *(const float2*)(bb + lane * 2);
    float di = dinv[row];
    float o0 = (dx0 * rs * wv.x + bv.x) * di;
    float o1 = (dx1 * rs * wv.y + bv.y) * di;
    u[(size_t)row * 64 + lane] = __floats2half2_rn(o0, o1);
}

// ---------------- propagate: Y[i] = scale * (X[i] + sum_{e in(i)} X[src]) ----------------
// fp16 in / fp16 out, fp32 accumulate. One wave per node, half2 per lane.

__global__ __launch_bounds__(256) void k_prop(const __half2* __restrict__ X,
                                              __half2* __restrict__ Y, const int* __restrict__ rp,
                                              const int* __restrict__ col,
                                              const float* __restrict__ dinv, int N, int squared) {
    int node = (blockIdx.x * 256 + threadIdx.x) >> 6;
    int lane = threadIdx.x & 63;
    if (node >= N) return;
    int e0 = rp[node], e1 = rp[node + 1];
    float2 acc = __half22float2(X[(size_t)node * 64 + lane]);
    int e = e0;
    for (; e + 1 < e1; e += 2) {
        int s0 = col[e];
        int s1 = col[e + 1];
        float2 g0 = __half22float2(X[(size_t)s0 * 64 + lane]);
        float2 g1 = __half22float2(X[(size_t)s1 * 64 + lane]);
        acc.x += g0.x + g1.x;
        acc.y += g0.y + g1.y;
    }
    if (e < e1) {
        int s0 = col[e];
        float2 g0 = __half22float2(X[(size_t)s0 * 64 + lane]);
        acc.x += g0.x;
        acc.y += g0.y;
    }
    float di = dinv[node];
    float sc = squared ? di * di : di;
    Y[(size_t)node * 64 + lane] = __floats2half2_rn(acc.x * sc, acc.y * sc);
}

// ---------------- W transpose + tall-skinny matmul ----------------

__global__ __launch_bounds__(256) void k_transW(const float* __restrict__ W,
                                                float* __restrict__ Wt) {
    int i = blockIdx.x * 256 + threadIdx.x;  // 16384
    int o = i >> 7, d = i & 127;
    Wt[d * DIM + o] = W[i];
}

#define ZS_STRIDE 132  // 128 + 4 pad: 16B-aligned rows, bank-spread

__global__ __launch_bounds__(256) void k_matmul(const __half* __restrict__ Z,
                                                const float* __restrict__ Wt,
                                                const float* __restrict__ b,
                                                float* __restrict__ out, int N) {
    __shared__ float Zs[64 * ZS_STRIDE];
    int tid = threadIdx.x;
    int rowBase = blockIdx.x * 64;
    // stage 64 rows of Z into LDS (fp16 global load, fp32 in LDS)
    for (int t = tid; t < 64 * 16; t += 256) {
        int r = t >> 4, c8 = (t & 15) << 3;  // 8 halves = 16B per thread
        int g = rowBase + r;
        float o[8];
        if (g < N) {
            float4 raw = *(const float4*)(Z + (size_t)g * DIM + c8);
            const __half2* h = (const __half2*)&raw;
#pragma unroll
            for (int k = 0; k < 4; k++) {
                float2 f = __half22float2(h[k]);
                o[2 * k] = f.x;
                o[2 * k + 1] = f.y;
            }
        } else {
#pragma unroll
            for (int k = 0; k < 8; k++) o[k] = 0.f;
        }
        float* dst = &Zs[r * ZS_STRIDE + c8];
#pragma unroll
        for (int k = 0; k < 8; k++) dst[k] = o[k];
    }
    __syncthreads();
    int ridx = tid >> 5;   // 0..7  -> rows ridx*8 .. ridx*8+7
    int cidx = tid & 31;   // 0..31 -> cols cidx*4 .. cidx*4+3
    int ob = cidx << 2;
    float acc[8][4];
#pragma unroll
    for (int j = 0; j < 8; j++)
#pragma unroll
        for (int c = 0; c < 4; c++) acc[j][c] = 0.f;
    const float* zrow = &Zs[(ridx * 8) * ZS_STRIDE];
#pragma unroll 2
    for (int d = 0; d < 128; d += 4) {
        float4 w0 = *(const float4*)(Wt + (d + 0) * DIM + ob);
        float4 w1 = *(const float4*)(Wt + (d + 1) * DIM + ob);
        float4 w2 = *(const float4*)(Wt + (d + 2) * DIM + ob);
        float4 w3 = *(const float4*)(Wt + (d + 3) * DIM + ob);
#pragma unroll
        for (int j = 0; j < 8; j++) {
            float4 z = *(const float4*)(&zrow[j * ZS_STRIDE + d]);
            acc[j][0] += z.x * w0.x + z.y * w1.x + z.z * w2.x + z.w * w3.x;
            acc[j][1] += z.x * w0.y + z.y * w1.y + z.z * w2.y + z.w * w3.y;
            acc[j][2] += z.x * w0.z + z.y * w1.z + z.z * w2.z + z.w * w3.z;
            acc[j][3] += z.x * w0.w + z.y * w1.w + z.z * w2.w + z.w * w3.w;
        }
    }
    float4 bv = *(const float4*)(b + ob);
#pragma unroll
    for (int j = 0; j < 8; j++) {
        int g = rowBase + ridx * 8 + j;
        if (g < N) {
            float4 o_;
            o_.x = acc[j][0] + bv.x;
            o_.y = acc[j][1] + bv.y;
            o_.z = acc[j][2] + bv.z;
            o_.w = acc[j][3] + bv.w;
            *(float4*)(out + (size_t)g * DIM + ob) = o_;
        }
    }
}

// ---------------- launch ----------------

extern "C" void kernel_launch(void* const* d_in, const int* in_sizes, int n_in, void* d_out,
                              int out_size, void* d_ws, size_t ws_size, hipStream_t stream) {
    const float* x = (const float*)d_in[0];
    const int* ei = (const int*)d_in[1];
    const float* ln_w = (const float*)d_in[2];
    const float* ln_b = (const float*)d_in[3];
    const float* W = (const float*)d_in[4];
    const float* b = (const float*)d_in[5];
    float* out = (float*)d_out;

    int N = in_sizes[0] / DIM;
    int E = in_sizes[1] / 2;

    // workspace carve-up (all 256B-aligned)
    char* p = (char*)d_ws;
    auto carve = [&](size_t bytes) {
        void* r = (void*)p;
        p += (bytes + 255) & ~(size_t)255;
        return r;
    };
    __half* u0 = (__half*)carve((size_t)N * DIM * 2);  // 25.6 MB ping
    __half* u1 = (__half*)carve((size_t)N * DIM * 2);  // 25.6 MB pong
    float* Wt = (float*)carve(DIM * DIM * 4);          // 64 KB
    int* deg = (int*)carve((size_t)N * 4);
    float* dinv = (float*)carve((size_t)N * 4);
    int* rp = (int*)carve((size_t)(N + 1) * 4);
    int* fp = (int*)carve((size_t)N * 4);
    int* tmp = (int*)carve((size_t)N * 4);
    int* bsum = (int*)carve(1024 * 4);
    int* col = (int*)carve((size_t)E * 4);             // 6.4 MB

    int gN = (N + 255) / 256;   // 391
    int gE = (E + 255) / 256;   // 6250
    int gW = (N + 3) / 4;       // wave-per-row kernels: 25000
    int gM = (N + 63) / 64;     // matmul row blocks: 1563

    k_deg_init<<<gN, 256, 0, stream>>>(deg, N);
    k_count<<<gE, 256, 0, stream>>>(ei, deg, E);
    k_dinv<<<gN, 256, 0, stream>>>(deg, dinv, N);
    k_scanA<<<gN, 256, 0, stream>>>(deg, tmp, bsum, N);
    k_scanB<<<1, 1024, 0, stream>>>(bsum, gN);
    k_scanC<<<gN, 256, 0, stream>>>(deg, tmp, bsum, rp, fp, N, E);
    k_fill<<<gE, 256, 0, stream>>>(ei, fp, col, E);
    k_transW<<<64, 256, 0, stream>>>(W, Wt);
    k_ln<<<gW, 256, 0, stream>>>(x, ln_w, ln_b, dinv, (__half2*)u0, N);
    // hop 1: u0 -> u1 (pre-scaled by dinv^2)
    k_prop<<<gW, 256, 0, stream>>>((const __half2*)u0, (__half2*)u1, rp, col, dinv, N, 1);
    // hop 2: u1 -> u0 (scaled by dinv)
    k_prop<<<gW, 256, 0, stream>>>((const __half2*)u1, (__half2*)u0, rp, col, dinv, N, 0);
    // out = z2 @ W^T + b (reads u0 fp16, writes d_out fp32)
    k_matmul<<<gM, 256, 0, stream>>>(u0, Wt, b, out, N);
}

// Round 3
// 328.209 us; speedup vs baseline: 1.9073x; 1.4546x over previous
//
#include <hip/hip_runtime.h>
#include <hip/hip_fp16.h>

#define DIM 128

// ---------------- degree count (atomic return = within-row rank) ----------------

__global__ __launch_bounds__(256) void k_zero(int* __restrict__ deg, int N) {
    int i = blockIdx.x * 256 + threadIdx.x;
    if (i < N) deg[i] = 0;
}

__global__ __launch_bounds__(256) void k_count_pos(const int* __restrict__ ei,
                                                   int* __restrict__ deg,
                                                   unsigned short* __restrict__ pos, int E) {
    int e = blockIdx.x * 256 + threadIdx.x;
    if (e < E) {
        int dst = ei[E + e];
        int p = atomicAdd(&deg[dst], 1);
        pos[e] = (unsigned short)p;
    }
}

// hierarchical exclusive scan of deg[i] -> row_ptr (edge-only CSR)
__global__ __launch_bounds__(256) void k_scanA(const int* __restrict__ deg, int* __restrict__ tmp,
                                               int* __restrict__ bsum, int N) {
    __shared__ int s[256];
    int tid = threadIdx.x;
    int i = blockIdx.x * 256 + tid;
    int v = (i < N) ? deg[i] : 0;
    s[tid] = v;
    __syncthreads();
    for (int off = 1; off < 256; off <<= 1) {
        int t = (tid >= off) ? s[tid - off] : 0;
        __syncthreads();
        s[tid] += t;
        __syncthreads();
    }
    if (i < N) tmp[i] = s[tid];  // inclusive within block
    if (tid == 255) bsum[blockIdx.x] = s[255];
}

__global__ __launch_bounds__(1024) void k_scanB(int* __restrict__ bsum, int nb) {
    __shared__ int s[1024];
    int tid = threadIdx.x;
    int v = (tid < nb) ? bsum[tid] : 0;
    s[tid] = v;
    __syncthreads();
    for (int off = 1; off < 1024; off <<= 1) {
        int t = (tid >= off) ? s[tid - off] : 0;
        __syncthreads();
        s[tid] += t;
        __syncthreads();
    }
    if (tid < nb) bsum[tid] = s[tid] - v;  // exclusive block offsets
}

__global__ __launch_bounds__(256) void k_scanC(const int* __restrict__ deg,
                                               const int* __restrict__ tmp,
                                               const int* __restrict__ bsum, int* __restrict__ rp,
                                               float* __restrict__ dinv, int N, int E) {
    int i = blockIdx.x * 256 + threadIdx.x;
    if (i < N) {
        int excl = bsum[blockIdx.x] + tmp[i] - deg[i];
        rp[i] = excl;
        dinv[i] = rsqrtf((float)(deg[i] + 1));  // +1: self-loop
    }
    if (i == 0) rp[N] = E;
}

// atomic-free CSR fill: position precomputed in k_count_pos
__global__ __launch_bounds__(256) void k_fill2(const int* __restrict__ ei,
                                               const int* __restrict__ rp,
                                               const unsigned short* __restrict__ pos,
                                               int* __restrict__ col, int E) {
    int e = blockIdx.x * 256 + threadIdx.x;
    if (e < E) {
        int src = ei[e];
        int dst = ei[E + e];
        col[rp[dst] + (int)pos[e]] = src;
    }
}

// ---------------- LayerNorm (+ pre-scale by dinv), fp16 output ----------------

__global__ __launch_bounds__(256) void k_ln(const float* __restrict__ x,
                                            const float* __restrict__ w,
                                            const float* __restrict__ bb,
                                            const float* __restrict__ dinv,
                                            __half2* __restrict__ u, int N) {
    int row = (blockIdx.x * 256 + threadIdx.x) >> 6;
    int lane = threadIdx.x & 63;
    if (row >= N) return;
    float2 v = *(const float2*)(x + (size_t)row * DIM + lane * 2);
    float s = v.x + v.y;
#pragma unroll
    for (int o = 32; o; o >>= 1) s += __shfl_xor(s, o, 64);
    float mu = s * (1.0f / 128.0f);
    float dx0 = v.x - mu, dx1 = v.y - mu;
    float ss = dx0 * dx0 + dx1 * dx1;
#pragma unroll
    for (int o = 32; o; o >>= 1) ss += __shfl_xor(ss, o, 64);
    float rs = rsqrtf(ss * (1.0f / 128.0f) + 1e-5f);
    float2 wv = *(const float2*)(w + lane * 2);
    float2 bv = *(const float2*)(bb + lane * 2);
    float di = dinv[row];
    float o0 = (dx0 * rs * wv.x + bv.x) * di;
    float o1 = (dx1 * rs * wv.y + bv.y) * di;
    u[(size_t)row * 64 + lane] = __floats2half2_rn(o0, o1);
}

// ---------------- propagate: Y[i] = scale * (X[i] + sum_{e in(i)} X[src]) ----------------
// fp16 in / fp16 out, fp32 accumulate. One wave per node, half2 per lane, 4-deep MLP.

__global__ __launch_bounds__(256) void k_prop(const __half2* __restrict__ X,
                                              __half2* __restrict__ Y, const int* __restrict__ rp,
                                              const int* __restrict__ col,
                                              const float* __restrict__ dinv, int N, int squared) {
    int node = (blockIdx.x * 256 + threadIdx.x) >> 6;
    int lane = threadIdx.x & 63;
    if (node >= N) return;
    int e0 = rp[node], e1 = rp[node + 1];
    float2 acc = __half22float2(X[(size_t)node * 64 + lane]);
    int e = e0;
    for (; e + 3 < e1; e += 4) {
        int s0 = col[e];
        int s1 = col[e + 1];
        int s2 = col[e + 2];
        int s3 = col[e + 3];
        float2 g0 = __half22float2(X[(size_t)s0 * 64 + lane]);
        float2 g1 = __half22float2(X[(size_t)s1 * 64 + lane]);
        float2 g2 = __half22float2(X[(size_t)s2 * 64 + lane]);
        float2 g3 = __half22float2(X[(size_t)s3 * 64 + lane]);
        acc.x += (g0.x + g1.x) + (g2.x + g3.x);
        acc.y += (g0.y + g1.y) + (g2.y + g3.y);
    }
    for (; e < e1; ++e) {
        int s0 = col[e];
        float2 g0 = __half22float2(X[(size_t)s0 * 64 + lane]);
        acc.x += g0.x;
        acc.y += g0.y;
    }
    float di = dinv[node];
    float sc = squared ? di * di : di;
    Y[(size_t)node * 64 + lane] = __floats2half2_rn(acc.x * sc, acc.y * sc);
}

// ---------------- W transpose + tall-skinny matmul ----------------

__global__ __launch_bounds__(256) void k_transW(const float* __restrict__ W,
                                                float* __restrict__ Wt) {
    int i = blockIdx.x * 256 + threadIdx.x;  // 16384
    int o = i >> 7, d = i & 127;
    Wt[d * DIM + o] = W[i];
}

#define ZS_STRIDE 132  // 128 + 4 pad: 16B-aligned rows, bank-spread

__global__ __launch_bounds__(256) void k_matmul(const __half* __restrict__ Z,
                                                const float* __restrict__ Wt,
                                                const float* __restrict__ b,
                                                float* __restrict__ out, int N) {
    __shared__ float Zs[64 * ZS_STRIDE];
    int tid = threadIdx.x;
    int rowBase = blockIdx.x * 64;
    // stage 64 rows of Z into LDS (fp16 global load, fp32 in LDS)
    for (int t = tid; t < 64 * 16; t += 256) {
        int r = t >> 4, c8 = (t & 15) << 3;  // 8 halves = 16B per thread
        int g = rowBase + r;
        float o[8];
        if (g < N) {
            float4 raw = *(const float4*)(Z + (size_t)g * DIM + c8);
            const __half2* h = (const __half2*)&raw;
#pragma unroll
            for (int k = 0; k < 4; k++) {
                float2 f = __half22float2(h[k]);
                o[2 * k] = f.x;
                o[2 * k + 1] = f.y;
            }
        } else {
#pragma unroll
            for (int k = 0; k < 8; k++) o[k] = 0.f;
        }
        float* dst = &Zs[r * ZS_STRIDE + c8];
#pragma unroll
        for (int k = 0; k < 8; k++) dst[k] = o[k];
    }
    __syncthreads();
    int ridx = tid >> 5;   // 0..7  -> rows ridx*8 .. ridx*8+7
    int cidx = tid & 31;   // 0..31 -> cols cidx*4 .. cidx*4+3
    int ob = cidx << 2;
    float acc[8][4];
#pragma unroll
    for (int j = 0; j < 8; j++)
#pragma unroll
        for (int c = 0; c < 4; c++) acc[j][c] = 0.f;
    const float* zrow = &Zs[(ridx * 8) * ZS_STRIDE];
#pragma unroll 2
    for (int d = 0; d < 128; d += 4) {
        float4 w0 = *(const float4*)(Wt + (d + 0) * DIM + ob);
        float4 w1 = *(const float4*)(Wt + (d + 1) * DIM + ob);
        float4 w2 = *(const float4*)(Wt + (d + 2) * DIM + ob);
        float4 w3 = *(const float4*)(Wt + (d + 3) * DIM + ob);
#pragma unroll
        for (int j = 0; j < 8; j++) {
            float4 z = *(const float4*)(&zrow[j * ZS_STRIDE + d]);
            acc[j][0] += z.x * w0.x + z.y * w1.x + z.z * w2.x + z.w * w3.x;
            acc[j][1] += z.x * w0.y + z.y * w1.y + z.z * w2.y + z.w * w3.y;
            acc[j][2] += z.x * w0.z + z.y * w1.z + z.z * w2.z + z.w * w3.z;
            acc[j][3] += z.x * w0.w + z.y * w1.w + z.z * w2.w + z.w * w3.w;
        }
    }
    float4 bv = *(const float4*)(b + ob);
#pragma unroll
    for (int j = 0; j < 8; j++) {
        int g = rowBase + ridx * 8 + j;
        if (g < N) {
            float4 o_;
            o_.x = acc[j][0] + bv.x;
            o_.y = acc[j][1] + bv.y;
            o_.z = acc[j][2] + bv.z;
            o_.w = acc[j][3] + bv.w;
            *(float4*)(out + (size_t)g * DIM + ob) = o_;
        }
    }
}

// ---------------- launch ----------------

extern "C" void kernel_launch(void* const* d_in, const int* in_sizes, int n_in, void* d_out,
                              int out_size, void* d_ws, size_t ws_size, hipStream_t stream) {
    const float* x = (const float*)d_in[0];
    const int* ei = (const int*)d_in[1];
    const float* ln_w = (const float*)d_in[2];
    const float* ln_b = (const float*)d_in[3];
    const float* W = (const float*)d_in[4];
    const float* b = (const float*)d_in[5];
    float* out = (float*)d_out;

    int N = in_sizes[0] / DIM;
    int E = in_sizes[1] / 2;

    // workspace carve-up (all 256B-aligned)
    char* p = (char*)d_ws;
    auto carve = [&](size_t bytes) {
        void* r = (void*)p;
        p += (bytes + 255) & ~(size_t)255;
        return r;
    };
    __half* u0 = (__half*)carve((size_t)N * DIM * 2);  // 25.6 MB ping
    __half* u1 = (__half*)carve((size_t)N * DIM * 2);  // 25.6 MB pong
    float* Wt = (float*)carve(DIM * DIM * 4);          // 64 KB
    int* deg = (int*)carve((size_t)N * 4);
    float* dinv = (float*)carve((size_t)N * 4);
    int* rp = (int*)carve((size_t)(N + 1) * 4);
    int* tmp = (int*)carve((size_t)N * 4);
    int* bsum = (int*)carve(1024 * 4);
    int* col = (int*)carve((size_t)E * 4);             // 6.4 MB

    // pos[] (E u16 = 3.2 MB) overlays u1: u1 is first written by prop hop 1,
    // which is after the last read of pos (k_fill2). No live overlap.
    unsigned short* pos = (unsigned short*)u1;

    int gN = (N + 255) / 256;   // 391
    int gE = (E + 255) / 256;   // 6250
    int gW = (N + 3) / 4;       // wave-per-row kernels: 25000
    int gM = (N + 63) / 64;     // matmul row blocks: 1563

    k_zero<<<gN, 256, 0, stream>>>(deg, N);
    k_count_pos<<<gE, 256, 0, stream>>>(ei, deg, pos, E);
    k_scanA<<<gN, 256, 0, stream>>>(deg, tmp, bsum, N);
    k_scanB<<<1, 1024, 0, stream>>>(bsum, gN);
    k_scanC<<<gN, 256, 0, stream>>>(deg, tmp, bsum, rp, dinv, N, E);
    k_fill2<<<gE, 256, 0, stream>>>(ei, rp, pos, col, E);
    k_transW<<<64, 256, 0, stream>>>(W, Wt);
    k_ln<<<gW, 256, 0, stream>>>(x, ln_w, ln_b, dinv, (__half2*)u0, N);
    // hop 1: u0 -> u1 (pre-scaled by dinv^2)   (clobbers pos — pos is dead here)
    k_prop<<<gW, 256, 0, stream>>>((const __half2*)u0, (__half2*)u1, rp, col, dinv, N, 1);
    // hop 2: u1 -> u0 (scaled by dinv)
    k_prop<<<gW, 256, 0, stream>>>((const __half2*)u1, (__half2*)u0, rp, col, dinv, N, 0);
    // out = z2 @ W^T + b (reads u0 fp16, writes d_out fp32)
    k_matmul<<<gM, 256, 0, stream>>>(u0, Wt, b, out, N);
}

// Round 4
// 272.159 us; speedup vs baseline: 2.3001x; 1.2059x over previous
//
#include <hip/hip_runtime.h>
#include <hip/hip_fp16.h>

#define DIM 128

typedef _Float16 half8 __attribute__((ext_vector_type(8)));
typedef float f32x4 __attribute__((ext_vector_type(4)));

// ---------------- degree count (atomic return = within-row rank) ----------------

__global__ __launch_bounds__(256) void k_zero(int* __restrict__ deg, int N) {
    int i = blockIdx.x * 256 + threadIdx.x;
    if (i < N) deg[i] = 0;
}

__global__ __launch_bounds__(256) void k_count_pos(const int* __restrict__ ei,
                                                   int* __restrict__ deg,
                                                   unsigned short* __restrict__ pos, int E) {
    int e = blockIdx.x * 256 + threadIdx.x;
    if (e < E) {
        int dst = ei[E + e];
        int p = atomicAdd(&deg[dst], 1);
        pos[e] = (unsigned short)p;
    }
}

// hierarchical exclusive scan of deg[i] -> row_ptr (edge-only CSR)
__global__ __launch_bounds__(256) void k_scanA(const int* __restrict__ deg, int* __restrict__ tmp,
                                               int* __restrict__ bsum, int N) {
    __shared__ int s[256];
    int tid = threadIdx.x;
    int i = blockIdx.x * 256 + tid;
    int v = (i < N) ? deg[i] : 0;
    s[tid] = v;
    __syncthreads();
    for (int off = 1; off < 256; off <<= 1) {
        int t = (tid >= off) ? s[tid - off] : 0;
        __syncthreads();
        s[tid] += t;
        __syncthreads();
    }
    if (i < N) tmp[i] = s[tid];  // inclusive within block
    if (tid == 255) bsum[blockIdx.x] = s[255];
}

__global__ __launch_bounds__(1024) void k_scanB(int* __restrict__ bsum, int nb) {
    __shared__ int s[1024];
    int tid = threadIdx.x;
    int v = (tid < nb) ? bsum[tid] : 0;
    s[tid] = v;
    __syncthreads();
    for (int off = 1; off < 1024; off <<= 1) {
        int t = (tid >= off) ? s[tid - off] : 0;
        __syncthreads();
        s[tid] += t;
        __syncthreads();
    }
    if (tid < nb) bsum[tid] = s[tid] - v;  // exclusive block offsets
}

__global__ __launch_bounds__(256) void k_scanC(const int* __restrict__ deg,
                                               const int* __restrict__ tmp,
                                               const int* __restrict__ bsum, int* __restrict__ rp,
                                               float* __restrict__ dinv, int N, int E) {
    int i = blockIdx.x * 256 + threadIdx.x;
    if (i < N) {
        int excl = bsum[blockIdx.x] + tmp[i] - deg[i];
        rp[i] = excl;
        dinv[i] = rsqrtf((float)(deg[i] + 1));  // +1: self-loop
    }
    if (i == 0) rp[N] = E;
}

// atomic-free CSR fill: position precomputed in k_count_pos
__global__ __launch_bounds__(256) void k_fill2(const int* __restrict__ ei,
                                               const int* __restrict__ rp,
                                               const unsigned short* __restrict__ pos,
                                               int* __restrict__ col, int E) {
    int e = blockIdx.x * 256 + threadIdx.x;
    if (e < E) {
        int src = ei[e];
        int dst = ei[E + e];
        col[rp[dst] + (int)pos[e]] = src;
    }
}

// ---------------- LayerNorm (+ pre-scale by dinv), fp16 output ----------------

__global__ __launch_bounds__(256) void k_ln(const float* __restrict__ x,
                                            const float* __restrict__ w,
                                            const float* __restrict__ bb,
                                            const float* __restrict__ dinv,
                                            __half2* __restrict__ u, int N) {
    int row = (blockIdx.x * 256 + threadIdx.x) >> 6;
    int lane = threadIdx.x & 63;
    if (row >= N) return;
    float2 v = *(const float2*)(x + (size_t)row * DIM + lane * 2);
    float s = v.x + v.y;
#pragma unroll
    for (int o = 32; o; o >>= 1) s += __shfl_xor(s, o, 64);
    float mu = s * (1.0f / 128.0f);
    float dx0 = v.x - mu, dx1 = v.y - mu;
    float ss = dx0 * dx0 + dx1 * dx1;
#pragma unroll
    for (int o = 32; o; o >>= 1) ss += __shfl_xor(ss, o, 64);
    float rs = rsqrtf(ss * (1.0f / 128.0f) + 1e-5f);
    float2 wv = *(const float2*)(w + lane * 2);
    float2 bv = *(const float2*)(bb + lane * 2);
    float di = dinv[row];
    float o0 = (dx0 * rs * wv.x + bv.x) * di;
    float o1 = (dx1 * rs * wv.y + bv.y) * di;
    u[(size_t)row * 64 + lane] = __floats2half2_rn(o0, o1);
}

// ---------------- propagate: Y[i] = scale * (X[i] + sum_{e in(i)} X[src]) ----------------
// fp16 in / fp16 out, fp32 accumulate. One wave per node, half2 per lane, 8-deep MLP.

__global__ __launch_bounds__(256) void k_prop(const __half2* __restrict__ X,
                                              __half2* __restrict__ Y, const int* __restrict__ rp,
                                              const int* __restrict__ col,
                                              const float* __restrict__ dinv, int N, int squared) {
    int node = (blockIdx.x * 256 + threadIdx.x) >> 6;
    int lane = threadIdx.x & 63;
    if (node >= N) return;
    int e0 = rp[node], e1 = rp[node + 1];
    float2 acc = __half22float2(X[(size_t)node * 64 + lane]);
    int e = e0;
    for (; e + 7 < e1; e += 8) {
        int s0 = col[e + 0], s1 = col[e + 1], s2 = col[e + 2], s3 = col[e + 3];
        int s4 = col[e + 4], s5 = col[e + 5], s6 = col[e + 6], s7 = col[e + 7];
        float2 g0 = __half22float2(X[(size_t)s0 * 64 + lane]);
        float2 g1 = __half22float2(X[(size_t)s1 * 64 + lane]);
        float2 g2 = __half22float2(X[(size_t)s2 * 64 + lane]);
        float2 g3 = __half22float2(X[(size_t)s3 * 64 + lane]);
        float2 g4 = __half22float2(X[(size_t)s4 * 64 + lane]);
        float2 g5 = __half22float2(X[(size_t)s5 * 64 + lane]);
        float2 g6 = __half22float2(X[(size_t)s6 * 64 + lane]);
        float2 g7 = __half22float2(X[(size_t)s7 * 64 + lane]);
        acc.x += ((g0.x + g1.x) + (g2.x + g3.x)) + ((g4.x + g5.x) + (g6.x + g7.x));
        acc.y += ((g0.y + g1.y) + (g2.y + g3.y)) + ((g4.y + g5.y) + (g6.y + g7.y));
    }
    for (; e + 1 < e1; e += 2) {
        int s0 = col[e], s1 = col[e + 1];
        float2 g0 = __half22float2(X[(size_t)s0 * 64 + lane]);
        float2 g1 = __half22float2(X[(size_t)s1 * 64 + lane]);
        acc.x += g0.x + g1.x;
        acc.y += g0.y + g1.y;
    }
    if (e < e1) {
        int s0 = col[e];
        float2 g0 = __half22float2(X[(size_t)s0 * 64 + lane]);
        acc.x += g0.x;
        acc.y += g0.y;
    }
    float di = dinv[node];
    float sc = squared ? di * di : di;
    Y[(size_t)node * 64 + lane] = __floats2half2_rn(acc.x * sc, acc.y * sc);
}

// ---------------- W fragment pre-pack + MFMA tall-skinny matmul ----------------
// pack[((tile*4+ks)*64 + lane)*8 + j] = (fp16) W[tile*16 + (lane&15)][ks*32 + 8*(lane>>4) + j]
// so each lane's B-fragment (n = lane&15, k = 8*(lane>>4)+j within the k-step) is one
// contiguous 16B load. Any consistent k-permutation cancels between A and B.

__global__ __launch_bounds__(256) void k_packW(const float* __restrict__ W,
                                               _Float16* __restrict__ pack) {
    int t = blockIdx.x * 256 + threadIdx.x;  // 0..2047
    if (t >= 2048) return;
    int lane = t & 63, ks = (t >> 6) & 3, tile = t >> 8;
    int wrow = tile * 16 + (lane & 15);
    int wcol = ks * 32 + 8 * (lane >> 4);
    float4 w0 = *(const float4*)(W + wrow * DIM + wcol);
    float4 w1 = *(const float4*)(W + wrow * DIM + wcol + 4);
    _Float16* dst = pack + (size_t)t * 8;
    dst[0] = (_Float16)w0.x; dst[1] = (_Float16)w0.y;
    dst[2] = (_Float16)w0.z; dst[3] = (_Float16)w0.w;
    dst[4] = (_Float16)w1.x; dst[5] = (_Float16)w1.y;
    dst[6] = (_Float16)w1.z; dst[7] = (_Float16)w1.w;
}

// 4 waves/block, 16 rows per wave, 64 rows/block. A from global, B from pack (L2-hot).
__global__ __launch_bounds__(256) void k_mm(const _Float16* __restrict__ Z,
                                            const _Float16* __restrict__ pack,
                                            const float* __restrict__ bias,
                                            float* __restrict__ out, int N) {
    int wave = threadIdx.x >> 6;
    int lane = threadIdx.x & 63;
    int rB = blockIdx.x * 64 + wave * 16;
    int r = rB + (lane & 15);
    bool rok = (r < N);
    // A-fragments for all 4 k-steps: lane holds Z[r][ks*32 + 8*(lane>>4) .. +7]
    half8 a[4];
    if (rok) {
        const _Float16* zr = Z + (size_t)r * DIM + 8 * (lane >> 4);
#pragma unroll
        for (int ks = 0; ks < 4; ks++) a[ks] = *(const half8*)(zr + ks * 32);
    } else {
#pragma unroll
        for (int ks = 0; ks < 4; ks++)
#pragma unroll
            for (int j = 0; j < 8; j++) a[ks][j] = (_Float16)0;
    }
    int row0 = rB + (lane >> 4) * 4;
#pragma unroll
    for (int tile = 0; tile < 8; tile++) {
        f32x4 d = {0.f, 0.f, 0.f, 0.f};
#pragma unroll
        for (int ks = 0; ks < 4; ks++) {
            half8 bf = *(const half8*)(pack + ((size_t)((tile * 4 + ks) * 64 + lane)) * 8);
            d = __builtin_amdgcn_mfma_f32_16x16x32_f16(a[ks], bf, d, 0, 0, 0);
        }
        int c = tile * 16 + (lane & 15);
        float bv = bias[c];
#pragma unroll
        for (int j = 0; j < 4; j++) {
            int rr = row0 + j;
            if (rr < N) out[(size_t)rr * DIM + c] = d[j] + bv;
        }
    }
}

// ---------------- launch ----------------

extern "C" void kernel_launch(void* const* d_in, const int* in_sizes, int n_in, void* d_out,
                              int out_size, void* d_ws, size_t ws_size, hipStream_t stream) {
    const float* x = (const float*)d_in[0];
    const int* ei = (const int*)d_in[1];
    const float* ln_w = (const float*)d_in[2];
    const float* ln_b = (const float*)d_in[3];
    const float* W = (const float*)d_in[4];
    const float* b = (const float*)d_in[5];
    float* out = (float*)d_out;

    int N = in_sizes[0] / DIM;
    int E = in_sizes[1] / 2;

    // workspace carve-up (all 256B-aligned)
    char* p = (char*)d_ws;
    auto carve = [&](size_t bytes) {
        void* r = (void*)p;
        p += (bytes + 255) & ~(size_t)255;
        return r;
    };
    __half* u0 = (__half*)carve((size_t)N * DIM * 2);  // 25.6 MB ping
    __half* u1 = (__half*)carve((size_t)N * DIM * 2);  // 25.6 MB pong
    _Float16* pack = (_Float16*)carve(DIM * DIM * 2);  // 32 KB packed W fragments
    int* deg = (int*)carve((size_t)N * 4);
    float* dinv = (float*)carve((size_t)N * 4);
    int* rp = (int*)carve((size_t)(N + 1) * 4);
    int* tmp = (int*)carve((size_t)N * 4);
    int* bsum = (int*)carve(1024 * 4);
    int* col = (int*)carve((size_t)E * 4);             // 6.4 MB

    // pos[] (E u16 = 3.2 MB) overlays u1: u1 is first written by prop hop 1,
    // which is after the last read of pos (k_fill2). No live overlap.
    unsigned short* pos = (unsigned short*)u1;

    int gN = (N + 255) / 256;   // 391
    int gE = (E + 255) / 256;   // 6250
    int gW = (N + 3) / 4;       // wave-per-row kernels: 25000
    int gM = (N + 63) / 64;     // matmul row blocks: 1563

    k_zero<<<gN, 256, 0, stream>>>(deg, N);
    k_count_pos<<<gE, 256, 0, stream>>>(ei, deg, pos, E);
    k_scanA<<<gN, 256, 0, stream>>>(deg, tmp, bsum, N);
    k_scanB<<<1, 1024, 0, stream>>>(bsum, gN);
    k_scanC<<<gN, 256, 0, stream>>>(deg, tmp, bsum, rp, dinv, N, E);
    k_fill2<<<gE, 256, 0, stream>>>(ei, rp, pos, col, E);
    k_packW<<<8, 256, 0, stream>>>(W, pack);
    k_ln<<<gW, 256, 0, stream>>>(x, ln_w, ln_b, dinv, (__half2*)u0, N);
    // hop 1: u0 -> u1 (pre-scaled by dinv^2)   (clobbers pos — pos is dead here)
    k_prop<<<gW, 256, 0, stream>>>((const __half2*)u0, (__half2*)u1, rp, col, dinv, N, 1);
    // hop 2: u1 -> u0 (scaled by dinv)
    k_prop<<<gW, 256, 0, stream>>>((const __half2*)u1, (__half2*)u0, rp, col, dinv, N, 0);
    // out = z2 @ W^T + b  (MFMA fp16, fp32 accumulate)
    k_mm<<<gM, 256, 0, stream>>>((const _Float16*)u0, pack, b, out, N);
}

// Round 5
// 270.528 us; speedup vs baseline: 2.3139x; 1.0060x over previous
//
#include <hip/hip_runtime.h>
#include <hip/hip_fp16.h>

#define DIM 128
#define DPAD 16  // one deg counter per 64B cache line

typedef _Float16 half8 __attribute__((ext_vector_type(8)));
typedef float f32x4 __attribute__((ext_vector_type(4)));

// ---------------- degree count (atomic return = within-row rank) ----------------
// deg counters padded to 1 per 64B line: 1.6M atomics over 100k lines instead of
// 6.25k lines -> 16x more line-level parallelism at the coherence point.

__global__ __launch_bounds__(256) void k_zero(int* __restrict__ degp, int n) {
    int i = blockIdx.x * 256 + threadIdx.x;
    if (i < n) degp[i] = 0;
}

__global__ __launch_bounds__(256) void k_count_pos(const int* __restrict__ ei,
                                                   int* __restrict__ degp,
                                                   unsigned short* __restrict__ pos, int E) {
    int e = blockIdx.x * 256 + threadIdx.x;
    if (e < E) {
        int dst = ei[E + e];
        int p = atomicAdd(&degp[dst << 4], 1);
        pos[e] = (unsigned short)p;
    }
}

// hierarchical exclusive scan of deg[i] -> row_ptr (edge-only CSR)
__global__ __launch_bounds__(256) void k_scanA(const int* __restrict__ degp, int* __restrict__ tmp,
                                               int* __restrict__ bsum, int N) {
    __shared__ int s[256];
    int tid = threadIdx.x;
    int i = blockIdx.x * 256 + tid;
    int v = (i < N) ? degp[i << 4] : 0;
    s[tid] = v;
    __syncthreads();
    for (int off = 1; off < 256; off <<= 1) {
        int t = (tid >= off) ? s[tid - off] : 0;
        __syncthreads();
        s[tid] += t;
        __syncthreads();
    }
    if (i < N) tmp[i] = s[tid];  // inclusive within block
    if (tid == 255) bsum[blockIdx.x] = s[255];
}

__global__ __launch_bounds__(1024) void k_scanB(int* __restrict__ bsum, int nb) {
    __shared__ int s[1024];
    int tid = threadIdx.x;
    int v = (tid < nb) ? bsum[tid] : 0;
    s[tid] = v;
    __syncthreads();
    for (int off = 1; off < 1024; off <<= 1) {
        int t = (tid >= off) ? s[tid - off] : 0;
        __syncthreads();
        s[tid] += t;
        __syncthreads();
    }
    if (tid < nb) bsum[tid] = s[tid] - v;  // exclusive block offsets
}

__global__ __launch_bounds__(256) void k_scanC(const int* __restrict__ degp,
                                               const int* __restrict__ tmp,
                                               const int* __restrict__ bsum, int* __restrict__ rp,
                                               float* __restrict__ dinv, int N, int E) {
    int i = blockIdx.x * 256 + threadIdx.x;
    if (i < N) {
        int d = degp[i << 4];
        int excl = bsum[blockIdx.x] + tmp[i] - d;
        rp[i] = excl;
        dinv[i] = rsqrtf((float)(d + 1));  // +1: self-loop
    }
    if (i == 0) rp[N] = E;
}

// atomic-free CSR fill: position precomputed in k_count_pos
__global__ __launch_bounds__(256) void k_fill2(const int* __restrict__ ei,
                                               const int* __restrict__ rp,
                                               const unsigned short* __restrict__ pos,
                                               int* __restrict__ col, int E) {
    int e = blockIdx.x * 256 + threadIdx.x;
    if (e < E) {
        int src = ei[e];
        int dst = ei[E + e];
        col[rp[dst] + (int)pos[e]] = src;
    }
}

// ---------------- LayerNorm (+ pre-scale by dinv), fp16 output ----------------

__global__ __launch_bounds__(256) void k_ln(const float* __restrict__ x,
                                            const float* __restrict__ w,
                                            const float* __restrict__ bb,
                                            const float* __restrict__ dinv,
                                            __half2* __restrict__ u, int N) {
    int row = (blockIdx.x * 256 + threadIdx.x) >> 6;
    int lane = threadIdx.x & 63;
    if (row >= N) return;
    float2 v = *(const float2*)(x + (size_t)row * DIM + lane * 2);
    float s = v.x + v.y;
#pragma unroll
    for (int o = 32; o; o >>= 1) s += __shfl_xor(s, o, 64);
    float mu = s * (1.0f / 128.0f);
    float dx0 = v.x - mu, dx1 = v.y - mu;
    float ss = dx0 * dx0 + dx1 * dx1;
#pragma unroll
    for (int o = 32; o; o >>= 1) ss += __shfl_xor(ss, o, 64);
    float rs = rsqrtf(ss * (1.0f / 128.0f) + 1e-5f);
    float2 wv = *(const float2*)(w + lane * 2);
    float2 bv = *(const float2*)(bb + lane * 2);
    float di = dinv[row];
    float o0 = (dx0 * rs * wv.x + bv.x) * di;
    float o1 = (dx1 * rs * wv.y + bv.y) * di;
    u[(size_t)row * 64 + lane] = __floats2half2_rn(o0, o1);
}

// ---------------- propagate: Y[i] = scale * (X[i] + sum_{e in(i)} X[src]) ----------------
// fp16 in / fp16 out, fp32 accumulate. One wave per node, half2 per lane, 8-deep MLP.

__global__ __launch_bounds__(256) void k_prop(const __half2* __restrict__ X,
                                              __half2* __restrict__ Y, const int* __restrict__ rp,
                                              const int* __restrict__ col,
                                              const float* __restrict__ dinv, int N, int squared) {
    int node = (blockIdx.x * 256 + threadIdx.x) >> 6;
    int lane = threadIdx.x & 63;
    if (node >= N) return;
    int e0 = rp[node], e1 = rp[node + 1];
    float2 acc = __half22float2(X[(size_t)node * 64 + lane]);
    int e = e0;
    for (; e + 7 < e1; e += 8) {
        int s0 = col[e + 0], s1 = col[e + 1], s2 = col[e + 2], s3 = col[e + 3];
        int s4 = col[e + 4], s5 = col[e + 5], s6 = col[e + 6], s7 = col[e + 7];
        float2 g0 = __half22float2(X[(size_t)s0 * 64 + lane]);
        float2 g1 = __half22float2(X[(size_t)s1 * 64 + lane]);
        float2 g2 = __half22float2(X[(size_t)s2 * 64 + lane]);
        float2 g3 = __half22float2(X[(size_t)s3 * 64 + lane]);
        float2 g4 = __half22float2(X[(size_t)s4 * 64 + lane]);
        float2 g5 = __half22float2(X[(size_t)s5 * 64 + lane]);
        float2 g6 = __half22float2(X[(size_t)s6 * 64 + lane]);
        float2 g7 = __half22float2(X[(size_t)s7 * 64 + lane]);
        acc.x += ((g0.x + g1.x) + (g2.x + g3.x)) + ((g4.x + g5.x) + (g6.x + g7.x));
        acc.y += ((g0.y + g1.y) + (g2.y + g3.y)) + ((g4.y + g5.y) + (g6.y + g7.y));
    }
    for (; e + 1 < e1; e += 2) {
        int s0 = col[e], s1 = col[e + 1];
        float2 g0 = __half22float2(X[(size_t)s0 * 64 + lane]);
        float2 g1 = __half22float2(X[(size_t)s1 * 64 + lane]);
        acc.x += g0.x + g1.x;
        acc.y += g0.y + g1.y;
    }
    if (e < e1) {
        int s0 = col[e];
        float2 g0 = __half22float2(X[(size_t)s0 * 64 + lane]);
        acc.x += g0.x;
        acc.y += g0.y;
    }
    float di = dinv[node];
    float sc = squared ? di * di : di;
    Y[(size_t)node * 64 + lane] = __floats2half2_rn(acc.x * sc, acc.y * sc);
}

// ---------------- W fragment pre-pack + MFMA tall-skinny matmul ----------------
// pack[((tile*4+ks)*64 + lane)*8 + j] = (fp16) W[tile*16 + (lane&15)][ks*32 + 8*(lane>>4) + j]

__global__ __launch_bounds__(256) void k_packW(const float* __restrict__ W,
                                               _Float16* __restrict__ pack) {
    int t = blockIdx.x * 256 + threadIdx.x;  // 0..2047
    if (t >= 2048) return;
    int lane = t & 63, ks = (t >> 6) & 3, tile = t >> 8;
    int wrow = tile * 16 + (lane & 15);
    int wcol = ks * 32 + 8 * (lane >> 4);
    float4 w0 = *(const float4*)(W + wrow * DIM + wcol);
    float4 w1 = *(const float4*)(W + wrow * DIM + wcol + 4);
    _Float16* dst = pack + (size_t)t * 8;
    dst[0] = (_Float16)w0.x; dst[1] = (_Float16)w0.y;
    dst[2] = (_Float16)w0.z; dst[3] = (_Float16)w0.w;
    dst[4] = (_Float16)w1.x; dst[5] = (_Float16)w1.y;
    dst[6] = (_Float16)w1.z; dst[7] = (_Float16)w1.w;
}

// 4 waves/block, 16 rows per wave, 64 rows/block. A from global, B from pack (L2-hot).
__global__ __launch_bounds__(256) void k_mm(const _Float16* __restrict__ Z,
                                            const _Float16* __restrict__ pack,
                                            const float* __restrict__ bias,
                                            float* __restrict__ out, int N) {
    int wave = threadIdx.x >> 6;
    int lane = threadIdx.x & 63;
    int rB = blockIdx.x * 64 + wave * 16;
    int r = rB + (lane & 15);
    bool rok = (r < N);
    half8 a[4];
    if (rok) {
        const _Float16* zr = Z + (size_t)r * DIM + 8 * (lane >> 4);
#pragma unroll
        for (int ks = 0; ks < 4; ks++) a[ks] = *(const half8*)(zr + ks * 32);
    } else {
#pragma unroll
        for (int ks = 0; ks < 4; ks++)
#pragma unroll
            for (int j = 0; j < 8; j++) a[ks][j] = (_Float16)0;
    }
    int row0 = rB + (lane >> 4) * 4;
#pragma unroll
    for (int tile = 0; tile < 8; tile++) {
        f32x4 d = {0.f, 0.f, 0.f, 0.f};
#pragma unroll
        for (int ks = 0; ks < 4; ks++) {
            half8 bf = *(const half8*)(pack + ((size_t)((tile * 4 + ks) * 64 + lane)) * 8);
            d = __builtin_amdgcn_mfma_f32_16x16x32_f16(a[ks], bf, d, 0, 0, 0);
        }
        int c = tile * 16 + (lane & 15);
        float bv = bias[c];
#pragma unroll
        for (int j = 0; j < 4; j++) {
            int rr = row0 + j;
            if (rr < N) out[(size_t)rr * DIM + c] = d[j] + bv;
        }
    }
}

// ---------------- launch ----------------

extern "C" void kernel_launch(void* const* d_in, const int* in_sizes, int n_in, void* d_out,
                              int out_size, void* d_ws, size_t ws_size, hipStream_t stream) {
    const float* x = (const float*)d_in[0];
    const int* ei = (const int*)d_in[1];
    const float* ln_w = (const float*)d_in[2];
    const float* ln_b = (const float*)d_in[3];
    const float* W = (const float*)d_in[4];
    const float* b = (const float*)d_in[5];
    float* out = (float*)d_out;

    int N = in_sizes[0] / DIM;
    int E = in_sizes[1] / 2;

    // workspace carve-up (all 256B-aligned)
    char* p = (char*)d_ws;
    auto carve = [&](size_t bytes) {
        void* r = (void*)p;
        p += (bytes + 255) & ~(size_t)255;
        return r;
    };
    __half* u0 = (__half*)carve((size_t)N * DIM * 2);      // 25.6 MB ping
    __half* u1 = (__half*)carve((size_t)N * DIM * 2);      // 25.6 MB pong
    _Float16* pack = (_Float16*)carve(DIM * DIM * 2);      // 32 KB packed W fragments
    int* degp = (int*)carve((size_t)N * DPAD * 4);         // 6.4 MB padded counters
    float* dinv = (float*)carve((size_t)N * 4);
    int* rp = (int*)carve((size_t)(N + 1) * 4);
    int* tmp = (int*)carve((size_t)N * 4);
    int* bsum = (int*)carve(1024 * 4);
    int* col = (int*)carve((size_t)E * 4);                 // 6.4 MB

    // pos[] (E u16 = 3.2 MB) overlays u1: u1 is first written by prop hop 1,
    // which is after the last read of pos (k_fill2). No live overlap.
    unsigned short* pos = (unsigned short*)u1;

    int gN = (N + 255) / 256;            // 391
    int gE = (E + 255) / 256;            // 6250
    int gZ = (N * DPAD + 255) / 256;     // 6250 (zero padded counters)
    int gW = (N + 3) / 4;                // wave-per-row kernels: 25000
    int gM = (N + 63) / 64;              // matmul row blocks: 1563

    k_zero<<<gZ, 256, 0, stream>>>(degp, N * DPAD);
    k_count_pos<<<gE, 256, 0, stream>>>(ei, degp, pos, E);
    k_scanA<<<gN, 256, 0, stream>>>(degp, tmp, bsum, N);
    k_scanB<<<1, 1024, 0, stream>>>(bsum, gN);
    k_scanC<<<gN, 256, 0, stream>>>(degp, tmp, bsum, rp, dinv, N, E);
    k_fill2<<<gE, 256, 0, stream>>>(ei, rp, pos, col, E);
    k_packW<<<8, 256, 0, stream>>>(W, pack);
    k_ln<<<gW, 256, 0, stream>>>(x, ln_w, ln_b, dinv, (__half2*)u0, N);
    // hop 1: u0 -> u1 (pre-scaled by dinv^2)   (clobbers pos — pos is dead here)
    k_prop<<<gW, 256, 0, stream>>>((const __half2*)u0, (__half2*)u1, rp, col, dinv, N, 1);
    // hop 2: u1 -> u0 (scaled by dinv)
    k_prop<<<gW, 256, 0, stream>>>((const __half2*)u1, (__half2*)u0, rp, col, dinv, N, 0);
    // out = z2 @ W^T + b  (MFMA fp16, fp32 accumulate)
    k_mm<<<gM, 256, 0, stream>>>((const _Float16*)u0, pack, b, out, N);
}

// Round 6
// 268.066 us; speedup vs baseline: 2.3352x; 1.0092x over previous
//
#include <hip/hip_runtime.h>
#include <hip/hip_fp16.h>

#define DIM 128

typedef _Float16 half8 __attribute__((ext_vector_type(8)));
typedef float f32x4 __attribute__((ext_vector_type(4)));

// ---------------- degree count (atomic return = within-row rank) ----------------

__global__ __launch_bounds__(256) void k_zero(int* __restrict__ deg, int n) {
    int i = blockIdx.x * 256 + threadIdx.x;
    if (i < n) deg[i] = 0;
}

__global__ __launch_bounds__(256) void k_count_pos(const int* __restrict__ ei,
                                                   int* __restrict__ deg,
                                                   unsigned short* __restrict__ pos, int E) {
    int e = blockIdx.x * 256 + threadIdx.x;
    if (e < E) {
        int dst = ei[E + e];
        int p = atomicAdd(&deg[dst], 1);
        pos[e] = (unsigned short)p;
    }
}

// hierarchical exclusive scan of deg[i] -> row_ptr (edge-only CSR)
__global__ __launch_bounds__(256) void k_scanA(const int* __restrict__ deg, int* __restrict__ tmp,
                                               int* __restrict__ bsum, int N) {
    __shared__ int s[256];
    int tid = threadIdx.x;
    int i = blockIdx.x * 256 + tid;
    int v = (i < N) ? deg[i] : 0;
    s[tid] = v;
    __syncthreads();
    for (int off = 1; off < 256; off <<= 1) {
        int t = (tid >= off) ? s[tid - off] : 0;
        __syncthreads();
        s[tid] += t;
        __syncthreads();
    }
    if (i < N) tmp[i] = s[tid];  // inclusive within block
    if (tid == 255) bsum[blockIdx.x] = s[255];
}

__global__ __launch_bounds__(1024) void k_scanB(int* __restrict__ bsum, int nb) {
    __shared__ int s[1024];
    int tid = threadIdx.x;
    int v = (tid < nb) ? bsum[tid] : 0;
    s[tid] = v;
    __syncthreads();
    for (int off = 1; off < 1024; off <<= 1) {
        int t = (tid >= off) ? s[tid - off] : 0;
        __syncthreads();
        s[tid] += t;
        __syncthreads();
    }
    if (tid < nb) bsum[tid] = s[tid] - v;  // exclusive block offsets
}

__global__ __launch_bounds__(256) void k_scanC(const int* __restrict__ deg,
                                               const int* __restrict__ tmp,
                                               const int* __restrict__ bsum, int* __restrict__ rp,
                                               float* __restrict__ dinv, int N, int E) {
    int i = blockIdx.x * 256 + threadIdx.x;
    if (i < N) {
        int d = deg[i];
        int excl = bsum[blockIdx.x] + tmp[i] - d;
        rp[i] = excl;
        dinv[i] = rsqrtf((float)(d + 1));  // +1: self-loop
    }
    if (i == 0) rp[N] = E;
}

// atomic-free CSR fill: position precomputed in k_count_pos
__global__ __launch_bounds__(256) void k_fill2(const int* __restrict__ ei,
                                               const int* __restrict__ rp,
                                               const unsigned short* __restrict__ pos,
                                               int* __restrict__ col, int E) {
    int e = blockIdx.x * 256 + threadIdx.x;
    if (e < E) {
        int src = ei[e];
        int dst = ei[E + e];
        col[rp[dst] + (int)pos[e]] = src;
    }
}

// ---------------- LayerNorm (+ pre-scale by dinv), fp16 output ----------------

__global__ __launch_bounds__(256) void k_ln(const float* __restrict__ x,
                                            const float* __restrict__ w,
                                            const float* __restrict__ bb,
                                            const float* __restrict__ dinv,
                                            __half2* __restrict__ u, int N) {
    int row = (blockIdx.x * 256 + threadIdx.x) >> 6;
    int lane = threadIdx.x & 63;
    if (row >= N) return;
    float2 v = *(const float2*)(x + (size_t)row * DIM + lane * 2);
    float s = v.x + v.y;
#pragma unroll
    for (int o = 32; o; o >>= 1) s += __shfl_xor(s, o, 64);
    float mu = s * (1.0f / 128.0f);
    float dx0 = v.x - mu, dx1 = v.y - mu;
    float ss = dx0 * dx0 + dx1 * dx1;
#pragma unroll
    for (int o = 32; o; o >>= 1) ss += __shfl_xor(ss, o, 64);
    float rs = rsqrtf(ss * (1.0f / 128.0f) + 1e-5f);
    float2 wv = *(const float2*)(w + lane * 2);
    float2 bv = *(const float2*)(bb + lane * 2);
    float di = dinv[row];
    float o0 = (dx0 * rs * wv.x + bv.x) * di;
    float o1 = (dx1 * rs * wv.y + bv.y) * di;
    u[(size_t)row * 64 + lane] = __floats2half2_rn(o0, o1);
}

// ---------------- propagate: Y[i] = scale * (X[i] + sum_{e in(i)} X[src]) ----------------
// One wave per node. Each lane loads 16B (half8): 16 lanes cover a 256B row, so one
// VMEM instruction gathers 4 edges' rows (sub = lane>>4 picks edge, q = lane&15 picks
// feature slice). Butterfly (xor 16, 32) combines the 4 sub-accumulators at the end.

__global__ __launch_bounds__(256) void k_prop(const _Float16* __restrict__ X,
                                              _Float16* __restrict__ Y,
                                              const int* __restrict__ rp,
                                              const int* __restrict__ col,
                                              const float* __restrict__ dinv, int N, int squared) {
    int node = (blockIdx.x * 256 + threadIdx.x) >> 6;
    int lane = threadIdx.x & 63;
    if (node >= N) return;
    int sub = lane >> 4;  // 0..3: which edge within a group of 4
    int q = lane & 15;    // feature slice: halves [8q .. 8q+7]
    const _Float16* xq = X + q * 8;
    half8 selfv = *(const half8*)(xq + (size_t)node * DIM);  // broadcast across subs
    int e0 = rp[node], e1 = rp[node + 1];
    float acc[8];
#pragma unroll
    for (int f = 0; f < 8; f++) acc[f] = 0.f;
    int e = e0;
    for (; e + 15 < e1; e += 16) {
        int s0 = col[e + sub];
        int s1 = col[e + 4 + sub];
        int s2 = col[e + 8 + sub];
        int s3 = col[e + 12 + sub];
        half8 g0 = *(const half8*)(xq + (size_t)s0 * DIM);
        half8 g1 = *(const half8*)(xq + (size_t)s1 * DIM);
        half8 g2 = *(const half8*)(xq + (size_t)s2 * DIM);
        half8 g3 = *(const half8*)(xq + (size_t)s3 * DIM);
#pragma unroll
        for (int f = 0; f < 8; f++)
            acc[f] += ((float)g0[f] + (float)g1[f]) + ((float)g2[f] + (float)g3[f]);
    }
    for (; e < e1; e += 4) {
        int idx = e + sub;
        if (idx < e1) {
            int s = col[idx];
            half8 g = *(const half8*)(xq + (size_t)s * DIM);
#pragma unroll
            for (int f = 0; f < 8; f++) acc[f] += (float)g[f];
        }
    }
    // combine the 4 sub-accumulators: lanes {q, q+16, q+32, q+48}
#pragma unroll
    for (int f = 0; f < 8; f++) acc[f] += __shfl_xor(acc[f], 16, 64);
#pragma unroll
    for (int f = 0; f < 8; f++) acc[f] += __shfl_xor(acc[f], 32, 64);
    float di = dinv[node];
    float sc = squared ? di * di : di;
    if (sub == 0) {
        half8 o;
#pragma unroll
        for (int f = 0; f < 8; f++) o[f] = (_Float16)(((float)selfv[f] + acc[f]) * sc);
        *(half8*)(Y + (size_t)node * DIM + q * 8) = o;
    }
}

// ---------------- W fragment pre-pack + MFMA tall-skinny matmul ----------------
// pack[((tile*4+ks)*64 + lane)*8 + j] = (fp16) W[tile*16 + (lane&15)][ks*32 + 8*(lane>>4) + j]

__global__ __launch_bounds__(256) void k_packW(const float* __restrict__ W,
                                               _Float16* __restrict__ pack) {
    int t = blockIdx.x * 256 + threadIdx.x;  // 0..2047
    if (t >= 2048) return;
    int lane = t & 63, ks = (t >> 6) & 3, tile = t >> 8;
    int wrow = tile * 16 + (lane & 15);
    int wcol = ks * 32 + 8 * (lane >> 4);
    float4 w0 = *(const float4*)(W + wrow * DIM + wcol);
    float4 w1 = *(const float4*)(W + wrow * DIM + wcol + 4);
    _Float16* dst = pack + (size_t)t * 8;
    dst[0] = (_Float16)w0.x; dst[1] = (_Float16)w0.y;
    dst[2] = (_Float16)w0.z; dst[3] = (_Float16)w0.w;
    dst[4] = (_Float16)w1.x; dst[5] = (_Float16)w1.y;
    dst[6] = (_Float16)w1.z; dst[7] = (_Float16)w1.w;
}

// 4 waves/block, 16 rows per wave, 64 rows/block. A from global, B from pack (L2-hot).
__global__ __launch_bounds__(256) void k_mm(const _Float16* __restrict__ Z,
                                            const _Float16* __restrict__ pack,
                                            const float* __restrict__ bias,
                                            float* __restrict__ out, int N) {
    int wave = threadIdx.x >> 6;
    int lane = threadIdx.x & 63;
    int rB = blockIdx.x * 64 + wave * 16;
    int r = rB + (lane & 15);
    bool rok = (r < N);
    half8 a[4];
    if (rok) {
        const _Float16* zr = Z + (size_t)r * DIM + 8 * (lane >> 4);
#pragma unroll
        for (int ks = 0; ks < 4; ks++) a[ks] = *(const half8*)(zr + ks * 32);
    } else {
#pragma unroll
        for (int ks = 0; ks < 4; ks++)
#pragma unroll
            for (int j = 0; j < 8; j++) a[ks][j] = (_Float16)0;
    }
    int row0 = rB + (lane >> 4) * 4;
#pragma unroll
    for (int tile = 0; tile < 8; tile++) {
        f32x4 d = {0.f, 0.f, 0.f, 0.f};
#pragma unroll
        for (int ks = 0; ks < 4; ks++) {
            half8 bf = *(const half8*)(pack + ((size_t)((tile * 4 + ks) * 64 + lane)) * 8);
            d = __builtin_amdgcn_mfma_f32_16x16x32_f16(a[ks], bf, d, 0, 0, 0);
        }
        int c = tile * 16 + (lane & 15);
        float bv = bias[c];
#pragma unroll
        for (int j = 0; j < 4; j++) {
            int rr = row0 + j;
            if (rr < N) out[(size_t)rr * DIM + c] = d[j] + bv;
        }
    }
}

// ---------------- launch ----------------

extern "C" void kernel_launch(void* const* d_in, const int* in_sizes, int n_in, void* d_out,
                              int out_size, void* d_ws, size_t ws_size, hipStream_t stream) {
    const float* x = (const float*)d_in[0];
    const int* ei = (const int*)d_in[1];
    const float* ln_w = (const float*)d_in[2];
    const float* ln_b = (const float*)d_in[3];
    const float* W = (const float*)d_in[4];
    const float* b = (const float*)d_in[5];
    float* out = (float*)d_out;

    int N = in_sizes[0] / DIM;
    int E = in_sizes[1] / 2;

    // workspace carve-up (all 256B-aligned)
    char* p = (char*)d_ws;
    auto carve = [&](size_t bytes) {
        void* r = (void*)p;
        p += (bytes + 255) & ~(size_t)255;
        return r;
    };
    __half* u0 = (__half*)carve((size_t)N * DIM * 2);      // 25.6 MB ping
    __half* u1 = (__half*)carve((size_t)N * DIM * 2);      // 25.6 MB pong
    _Float16* pack = (_Float16*)carve(DIM * DIM * 2);      // 32 KB packed W fragments
    int* deg = (int*)carve((size_t)N * 4);
    float* dinv = (float*)carve((size_t)N * 4);
    int* rp = (int*)carve((size_t)(N + 1) * 4);
    int* tmp = (int*)carve((size_t)N * 4);
    int* bsum = (int*)carve(1024 * 4);
    int* col = (int*)carve((size_t)E * 4);                 // 6.4 MB

    // pos[] (E u16 = 3.2 MB) overlays u1: u1 is first written by prop hop 1,
    // which is after the last read of pos (k_fill2). No live overlap.
    unsigned short* pos = (unsigned short*)u1;

    int gN = (N + 255) / 256;   // 391
    int gE = (E + 255) / 256;   // 6250
    int gW = (N + 3) / 4;       // wave-per-row kernels: 25000
    int gM = (N + 63) / 64;     // matmul row blocks: 1563

    k_zero<<<gN, 256, 0, stream>>>(deg, N);
    k_count_pos<<<gE, 256, 0, stream>>>(ei, deg, pos, E);
    k_scanA<<<gN, 256, 0, stream>>>(deg, tmp, bsum, N);
    k_scanB<<<1, 1024, 0, stream>>>(bsum, gN);
    k_scanC<<<gN, 256, 0, stream>>>(deg, tmp, bsum, rp, dinv, N, E);
    k_fill2<<<gE, 256, 0, stream>>>(ei, rp, pos, col, E);
    k_packW<<<8, 256, 0, stream>>>(W, pack);
    k_ln<<<gW, 256, 0, stream>>>(x, ln_w, ln_b, dinv, (__half2*)u0, N);
    // hop 1: u0 -> u1 (pre-scaled by dinv^2)   (clobbers pos — pos is dead here)
    k_prop<<<gW, 256, 0, stream>>>((const _Float16*)u0, (_Float16*)u1, rp, col, dinv, N, 1);
    // hop 2: u1 -> u0 (scaled by dinv)
    k_prop<<<gW, 256, 0, stream>>>((const _Float16*)u1, (_Float16*)u0, rp, col, dinv, N, 0);
    // out = z2 @ W^T + b  (MFMA fp16, fp32 accumulate)
    k_mm<<<gM, 256, 0, stream>>>((const _Float16*)u0, pack, b, out, N);
}

// Round 7
// 227.287 us; speedup vs baseline: 2.7542x; 1.1794x over previous
//
#include <hip/hip_runtime.h>
#include <hip/hip_fp16.h>

#define DIM 128
#define BKT_SHIFT 8    // 256 nodes per bucket
#define BKT_NODES 256
#define CHUNK 8192     // edges per S1/S3 block
#define MAXBUK 1024    // LDS histogram capacity (NBUK = ceil(N/256) must be <= this)

typedef _Float16 half8 __attribute__((ext_vector_type(8)));
typedef float f32x4 __attribute__((ext_vector_type(4)));

// ---------------- S1: per-chunk bucket histogram (LDS atomics only) ----------------

__global__ __launch_bounds__(256) void k_s1_hist(const int* __restrict__ ei, int* __restrict__ H,
                                                 int E, int NBUK, int NBLK) {
    __shared__ int hist[MAXBUK];
    int b = blockIdx.x, tid = threadIdx.x;
    for (int i = tid; i < NBUK; i += 256) hist[i] = 0;
    __syncthreads();
    int e0 = b * CHUNK, e1 = min(e0 + CHUNK, E);
    for (int e = e0 + tid; e < e1; e += 256) {
        int dst = ei[E + e];
        atomicAdd(&hist[dst >> BKT_SHIFT], 1);
    }
    __syncthreads();
    for (int k = tid; k < NBUK; k += 256) H[(size_t)k * NBLK + b] = hist[k];
}

// ---------------- S2: flat exclusive scan of H (bucket-major) ----------------

__global__ __launch_bounds__(256) void k_scanA(const int* __restrict__ in, int* __restrict__ tmp,
                                               int* __restrict__ bsum, int n) {
    __shared__ int s[256];
    int tid = threadIdx.x;
    int i = blockIdx.x * 256 + tid;
    int v = (i < n) ? in[i] : 0;
    s[tid] = v;
    __syncthreads();
    for (int off = 1; off < 256; off <<= 1) {
        int t = (tid >= off) ? s[tid - off] : 0;
        __syncthreads();
        s[tid] += t;
        __syncthreads();
    }
    if (i < n) tmp[i] = s[tid];  // inclusive within block
    if (tid == 255) bsum[blockIdx.x] = s[255];
}

__global__ __launch_bounds__(1024) void k_scanB(int* __restrict__ bsum, int nb) {
    __shared__ int s[1024];
    int tid = threadIdx.x;
    int v = (tid < nb) ? bsum[tid] : 0;
    s[tid] = v;
    __syncthreads();
    for (int off = 1; off < 1024; off <<= 1) {
        int t = (tid >= off) ? s[tid - off] : 0;
        __syncthreads();
        s[tid] += t;
        __syncthreads();
    }
    if (tid < nb) bsum[tid] = s[tid] - v;  // exclusive block offsets
}

// in-place: H[i] = exclusive_global(i) = bsum[blk] + tmp[i] - H[i]
__global__ __launch_bounds__(256) void k_scanE(int* __restrict__ H, const int* __restrict__ tmp,
                                               const int* __restrict__ bsum, int n) {
    int i = blockIdx.x * 256 + threadIdx.x;
    if (i < n) H[i] = bsum[blockIdx.x] + tmp[i] - H[i];
}

// ---------------- S3: scatter edges into bucket-sorted order ----------------

__global__ __launch_bounds__(256) void k_s3_scatter(const int* __restrict__ ei,
                                                    const int* __restrict__ H,
                                                    int* __restrict__ ssrc,
                                                    unsigned char* __restrict__ sdst, int E,
                                                    int NBUK, int NBLK) {
    __shared__ int off[MAXBUK];
    int b = blockIdx.x, tid = threadIdx.x;
    for (int k = tid; k < NBUK; k += 256) off[k] = H[(size_t)k * NBLK + b];
    __syncthreads();
    int e0 = b * CHUNK, e1 = min(e0 + CHUNK, E);
    for (int e = e0 + tid; e < e1; e += 256) {
        int src = ei[e];
        int dst = ei[E + e];
        int p = atomicAdd(&off[dst >> BKT_SHIFT], 1);
        ssrc[p] = src;
        sdst[p] = (unsigned char)(dst & (BKT_NODES - 1));
    }
}

// ---------------- S4: per-bucket CSR build + deg/dinv/rp ----------------

__global__ __launch_bounds__(256) void k_s4_build(const int* __restrict__ H,
                                                  const int* __restrict__ ssrc,
                                                  const unsigned char* __restrict__ sdst,
                                                  int* __restrict__ rp, float* __restrict__ dinv,
                                                  int* __restrict__ col, int N, int E, int NBUK,
                                                  int NBLK) {
    __shared__ int cnt[BKT_NODES];
    __shared__ int pos[BKT_NODES];
    __shared__ int s[BKT_NODES];
    int bkt = blockIdx.x, tid = threadIdx.x;
    int base = H[(size_t)bkt * NBLK];
    int endv = (bkt + 1 < NBUK) ? H[(size_t)(bkt + 1) * NBLK] : E;
    int m = endv - base;
    cnt[tid] = 0;
    __syncthreads();
    for (int i = tid; i < m; i += 256) atomicAdd(&cnt[sdst[base + i]], 1);
    __syncthreads();
    int v = cnt[tid];
    s[tid] = v;
    __syncthreads();
    for (int off = 1; off < 256; off <<= 1) {
        int t = (tid >= off) ? s[tid - off] : 0;
        __syncthreads();
        s[tid] += t;
        __syncthreads();
    }
    int excl = s[tid] - v;
    pos[tid] = excl;
    int node = bkt * BKT_NODES + tid;
    if (node < N) {
        rp[node] = base + excl;
        dinv[node] = rsqrtf((float)(v + 1));  // +1: self-loop
    }
    __syncthreads();
    for (int i = tid; i < m; i += 256) {
        int r = atomicAdd(&pos[sdst[base + i]], 1);
        col[base + r] = ssrc[base + i];
    }
    if (bkt == 0 && tid == 0) rp[N] = E;
}

// ---------------- LayerNorm (+ pre-scale by dinv), fp16 output ----------------

__global__ __launch_bounds__(256) void k_ln(const float* __restrict__ x,
                                            const float* __restrict__ w,
                                            const float* __restrict__ bb,
                                            const float* __restrict__ dinv,
                                            __half2* __restrict__ u, int N) {
    int row = (blockIdx.x * 256 + threadIdx.x) >> 6;
    int lane = threadIdx.x & 63;
    if (row >= N) return;
    float2 v = *(const float2*)(x + (size_t)row * DIM + lane * 2);
    float s = v.x + v.y;
#pragma unroll
    for (int o = 32; o; o >>= 1) s += __shfl_xor(s, o, 64);
    float mu = s * (1.0f / 128.0f);
    float dx0 = v.x - mu, dx1 = v.y - mu;
    float ss = dx0 * dx0 + dx1 * dx1;
#pragma unroll
    for (int o = 32; o; o >>= 1) ss += __shfl_xor(ss, o, 64);
    float rs = rsqrtf(ss * (1.0f / 128.0f) + 1e-5f);
    float2 wv = *(const float2*)(w + lane * 2);
    float2 bv = *(const float2*)(bb + lane * 2);
    float di = dinv[row];
    float o0 = (dx0 * rs * wv.x + bv.x) * di;
    float o1 = (dx1 * rs * wv.y + bv.y) * di;
    u[(size_t)row * 64 + lane] = __floats2half2_rn(o0, o1);
}

// ---------------- propagate: Y[i] = scale * (X[i] + sum_{e in(i)} X[src]) ----------------
// One wave per node; one VMEM instr gathers 4 edges' 256B rows (16 lanes x 16B each).

__global__ __launch_bounds__(256) void k_prop(const _Float16* __restrict__ X,
                                              _Float16* __restrict__ Y,
                                              const int* __restrict__ rp,
                                              const int* __restrict__ col,
                                              const float* __restrict__ dinv, int N, int squared) {
    int node = (blockIdx.x * 256 + threadIdx.x) >> 6;
    int lane = threadIdx.x & 63;
    if (node >= N) return;
    int sub = lane >> 4;  // 0..3: which edge within a group of 4
    int q = lane & 15;    // feature slice: halves [8q .. 8q+7]
    const _Float16* xq = X + q * 8;
    half8 selfv = *(const half8*)(xq + (size_t)node * DIM);
    int e0 = rp[node], e1 = rp[node + 1];
    float acc[8];
#pragma unroll
    for (int f = 0; f < 8; f++) acc[f] = 0.f;
    int e = e0;
    for (; e + 15 < e1; e += 16) {
        int s0 = col[e + sub];
        int s1 = col[e + 4 + sub];
        int s2 = col[e + 8 + sub];
        int s3 = col[e + 12 + sub];
        half8 g0 = *(const half8*)(xq + (size_t)s0 * DIM);
        half8 g1 = *(const half8*)(xq + (size_t)s1 * DIM);
        half8 g2 = *(const half8*)(xq + (size_t)s2 * DIM);
        half8 g3 = *(const half8*)(xq + (size_t)s3 * DIM);
#pragma unroll
        for (int f = 0; f < 8; f++)
            acc[f] += ((float)g0[f] + (float)g1[f]) + ((float)g2[f] + (float)g3[f]);
    }
    for (; e < e1; e += 4) {
        int idx = e + sub;
        if (idx < e1) {
            int s = col[idx];
            half8 g = *(const half8*)(xq + (size_t)s * DIM);
#pragma unroll
            for (int f = 0; f < 8; f++) acc[f] += (float)g[f];
        }
    }
#pragma unroll
    for (int f = 0; f < 8; f++) acc[f] += __shfl_xor(acc[f], 16, 64);
#pragma unroll
    for (int f = 0; f < 8; f++) acc[f] += __shfl_xor(acc[f], 32, 64);
    float di = dinv[node];
    float sc = squared ? di * di : di;
    if (sub == 0) {
        half8 o;
#pragma unroll
        for (int f = 0; f < 8; f++) o[f] = (_Float16)(((float)selfv[f] + acc[f]) * sc);
        *(half8*)(Y + (size_t)node * DIM + q * 8) = o;
    }
}

// ---------------- W fragment pre-pack + MFMA tall-skinny matmul ----------------
// pack[((tile*4+ks)*64 + lane)*8 + j] = (fp16) W[tile*16 + (lane&15)][ks*32 + 8*(lane>>4) + j]

__global__ __launch_bounds__(256) void k_packW(const float* __restrict__ W,
                                               _Float16* __restrict__ pack) {
    int t = blockIdx.x * 256 + threadIdx.x;  // 0..2047
    if (t >= 2048) return;
    int lane = t & 63, ks = (t >> 6) & 3, tile = t >> 8;
    int wrow = tile * 16 + (lane & 15);
    int wcol = ks * 32 + 8 * (lane >> 4);
    float4 w0 = *(const float4*)(W + wrow * DIM + wcol);
    float4 w1 = *(const float4*)(W + wrow * DIM + wcol + 4);
    _Float16* dst = pack + (size_t)t * 8;
    dst[0] = (_Float16)w0.x; dst[1] = (_Float16)w0.y;
    dst[2] = (_Float16)w0.z; dst[3] = (_Float16)w0.w;
    dst[4] = (_Float16)w1.x; dst[5] = (_Float16)w1.y;
    dst[6] = (_Float16)w1.z; dst[7] = (_Float16)w1.w;
}

// 4 waves/block, 16 rows per wave, 64 rows/block. A from global, B from pack (L2-hot).
__global__ __launch_bounds__(256) void k_mm(const _Float16* __restrict__ Z,
                                            const _Float16* __restrict__ pack,
                                            const float* __restrict__ bias,
                                            float* __restrict__ out, int N) {
    int wave = threadIdx.x >> 6;
    int lane = threadIdx.x & 63;
    int rB = blockIdx.x * 64 + wave * 16;
    int r = rB + (lane & 15);
    bool rok = (r < N);
    half8 a[4];
    if (rok) {
        const _Float16* zr = Z + (size_t)r * DIM + 8 * (lane >> 4);
#pragma unroll
        for (int ks = 0; ks < 4; ks++) a[ks] = *(const half8*)(zr + ks * 32);
    } else {
#pragma unroll
        for (int ks = 0; ks < 4; ks++)
#pragma unroll
            for (int j = 0; j < 8; j++) a[ks][j] = (_Float16)0;
    }
    int row0 = rB + (lane >> 4) * 4;
#pragma unroll
    for (int tile = 0; tile < 8; tile++) {
        f32x4 d = {0.f, 0.f, 0.f, 0.f};
#pragma unroll
        for (int ks = 0; ks < 4; ks++) {
            half8 bf = *(const half8*)(pack + ((size_t)((tile * 4 + ks) * 64 + lane)) * 8);
            d = __builtin_amdgcn_mfma_f32_16x16x32_f16(a[ks], bf, d, 0, 0, 0);
        }
        int c = tile * 16 + (lane & 15);
        float bv = bias[c];
#pragma unroll
        for (int j = 0; j < 4; j++) {
            int rr = row0 + j;
            if (rr < N) out[(size_t)rr * DIM + c] = d[j] + bv;
        }
    }
}

// ---------------- launch ----------------

extern "C" void kernel_launch(void* const* d_in, const int* in_sizes, int n_in, void* d_out,
                              int out_size, void* d_ws, size_t ws_size, hipStream_t stream) {
    const float* x = (const float*)d_in[0];
    const int* ei = (const int*)d_in[1];
    const float* ln_w = (const float*)d_in[2];
    const float* ln_b = (const float*)d_in[3];
    const float* W = (const float*)d_in[4];
    const float* b = (const float*)d_in[5];
    float* out = (float*)d_out;

    int N = in_sizes[0] / DIM;
    int E = in_sizes[1] / 2;

    int NBUK = (N + BKT_NODES - 1) / BKT_NODES;  // 391
    int NBLK = (E + CHUNK - 1) / CHUNK;          // 196
    int M = NBUK * NBLK;                         // 76,636
    int gScan = (M + 255) / 256;                 // 300 (<= 1024)

    // workspace carve-up (all 256B-aligned)
    char* p = (char*)d_ws;
    auto carve = [&](size_t bytes) {
        void* r = (void*)p;
        p += (bytes + 255) & ~(size_t)255;
        return r;
    };
    __half* u0 = (__half*)carve((size_t)N * DIM * 2);      // 25.6 MB ping
    __half* u1 = (__half*)carve((size_t)N * DIM * 2);      // 25.6 MB pong
    _Float16* pack = (_Float16*)carve(DIM * DIM * 2);      // 32 KB packed W fragments
    int* H = (int*)carve((size_t)M * 4);                   // 306 KB bucket histograms
    float* dinv = (float*)carve((size_t)N * 4);
    int* rp = (int*)carve((size_t)(N + 1) * 4);
    int* tmp = (int*)carve((size_t)(N > M ? N : M) * 4);
    int* bsum = (int*)carve(1024 * 4);
    int* col = (int*)carve((size_t)E * 4);                 // 6.4 MB

    // sorted-edge arrays overlay u1 (dead until prop hop 1 writes it)
    int* ssrc = (int*)u1;                                  // E ints = 6.4 MB
    unsigned char* sdst = (unsigned char*)u1 + ((size_t)E * 4 + 255 & ~(size_t)255);  // E bytes

    int gW = (N + 3) / 4;    // wave-per-row kernels: 25000
    int gM = (N + 63) / 64;  // matmul row blocks: 1563

    k_s1_hist<<<NBLK, 256, 0, stream>>>(ei, H, E, NBUK, NBLK);
    k_scanA<<<gScan, 256, 0, stream>>>(H, tmp, bsum, M);
    k_scanB<<<1, 1024, 0, stream>>>(bsum, gScan);
    k_scanE<<<gScan, 256, 0, stream>>>(H, tmp, bsum, M);
    k_s3_scatter<<<NBLK, 256, 0, stream>>>(ei, H, ssrc, sdst, E, NBUK, NBLK);
    k_s4_build<<<NBUK, 256, 0, stream>>>(H, ssrc, sdst, rp, dinv, col, N, E, NBUK, NBLK);
    k_packW<<<8, 256, 0, stream>>>(W, pack);
    k_ln<<<gW, 256, 0, stream>>>(x, ln_w, ln_b, dinv, (__half2*)u0, N);
    // hop 1: u0 -> u1 (pre-scaled by dinv^2)   (clobbers ssrc/sdst — dead here)
    k_prop<<<gW, 256, 0, stream>>>((const _Float16*)u0, (_Float16*)u1, rp, col, dinv, N, 1);
    // hop 2: u1 -> u0 (scaled by dinv)
    k_prop<<<gW, 256, 0, stream>>>((const _Float16*)u1, (_Float16*)u0, rp, col, dinv, N, 0);
    // out = z2 @ W^T + b  (MFMA fp16, fp32 accumulate)
    k_mm<<<gM, 256, 0, stream>>>((const _Float16*)u0, pack, b, out, N);
}

// Round 8
// 225.681 us; speedup vs baseline: 2.7738x; 1.0071x over previous
//
#include <hip/hip_runtime.h>
#include <hip/hip_fp16.h>

#define DIM 128
#define BKT_SHIFT 8    // 256 nodes per bucket
#define BKT_NODES 256
#define CHUNK 8192     // edges per S1/S3 block
#define MAXBUK 1024    // LDS histogram capacity (NBUK = ceil(N/256) must be <= this)

typedef _Float16 half8 __attribute__((ext_vector_type(8)));
typedef float f32x4 __attribute__((ext_vector_type(4)));

// ---------------- S1: per-chunk bucket histogram (LDS atomics only) ----------------

__global__ __launch_bounds__(256) void k_s1_hist(const int* __restrict__ ei, int* __restrict__ H,
                                                 int E, int NBUK, int NBLK) {
    __shared__ int hist[MAXBUK];
    int b = blockIdx.x, tid = threadIdx.x;
    for (int i = tid; i < NBUK; i += 256) hist[i] = 0;
    __syncthreads();
    int e0 = b * CHUNK, e1 = min(e0 + CHUNK, E);
    for (int e = e0 + tid; e < e1; e += 256) {
        int dst = ei[E + e];
        atomicAdd(&hist[dst >> BKT_SHIFT], 1);
    }
    __syncthreads();
    for (int k = tid; k < NBUK; k += 256) H[(size_t)k * NBLK + b] = hist[k];
}

// ---------------- S2: flat exclusive scan of H (bucket-major) ----------------

__global__ __launch_bounds__(256) void k_scanA(const int* __restrict__ in, int* __restrict__ tmp,
                                               int* __restrict__ bsum, int n) {
    __shared__ int s[256];
    int tid = threadIdx.x;
    int i = blockIdx.x * 256 + tid;
    int v = (i < n) ? in[i] : 0;
    s[tid] = v;
    __syncthreads();
    for (int off = 1; off < 256; off <<= 1) {
        int t = (tid >= off) ? s[tid - off] : 0;
        __syncthreads();
        s[tid] += t;
        __syncthreads();
    }
    if (i < n) tmp[i] = s[tid];  // inclusive within block
    if (tid == 255) bsum[blockIdx.x] = s[255];
}

__global__ __launch_bounds__(1024) void k_scanB(int* __restrict__ bsum, int nb) {
    __shared__ int s[1024];
    int tid = threadIdx.x;
    int v = (tid < nb) ? bsum[tid] : 0;
    s[tid] = v;
    __syncthreads();
    for (int off = 1; off < 1024; off <<= 1) {
        int t = (tid >= off) ? s[tid - off] : 0;
        __syncthreads();
        s[tid] += t;
        __syncthreads();
    }
    if (tid < nb) bsum[tid] = s[tid] - v;  // exclusive block offsets
}

// in-place: H[i] = exclusive_global(i) = bsum[blk] + tmp[i] - H[i]
__global__ __launch_bounds__(256) void k_scanE(int* __restrict__ H, const int* __restrict__ tmp,
                                               const int* __restrict__ bsum, int n) {
    int i = blockIdx.x * 256 + threadIdx.x;
    if (i < n) H[i] = bsum[blockIdx.x] + tmp[i] - H[i];
}

// ---------------- S3: scatter edges into bucket-sorted order ----------------

__global__ __launch_bounds__(256) void k_s3_scatter(const int* __restrict__ ei,
                                                    const int* __restrict__ H,
                                                    int* __restrict__ ssrc,
                                                    unsigned char* __restrict__ sdst, int E,
                                                    int NBUK, int NBLK) {
    __shared__ int off[MAXBUK];
    int b = blockIdx.x, tid = threadIdx.x;
    for (int k = tid; k < NBUK; k += 256) off[k] = H[(size_t)k * NBLK + b];
    __syncthreads();
    int e0 = b * CHUNK, e1 = min(e0 + CHUNK, E);
    for (int e = e0 + tid; e < e1; e += 256) {
        int src = ei[e];
        int dst = ei[E + e];
        int p = atomicAdd(&off[dst >> BKT_SHIFT], 1);
        ssrc[p] = src;
        sdst[p] = (unsigned char)(dst & (BKT_NODES - 1));
    }
}

// ---------------- S4: per-bucket CSR build + deg/dinv/rp ----------------

__global__ __launch_bounds__(256) void k_s4_build(const int* __restrict__ H,
                                                  const int* __restrict__ ssrc,
                                                  const unsigned char* __restrict__ sdst,
                                                  int* __restrict__ rp, float* __restrict__ dinv,
                                                  int* __restrict__ col, int N, int E, int NBUK,
                                                  int NBLK) {
    __shared__ int cnt[BKT_NODES];
    __shared__ int pos[BKT_NODES];
    __shared__ int s[BKT_NODES];
    int bkt = blockIdx.x, tid = threadIdx.x;
    int base = H[(size_t)bkt * NBLK];
    int endv = (bkt + 1 < NBUK) ? H[(size_t)(bkt + 1) * NBLK] : E;
    int m = endv - base;
    cnt[tid] = 0;
    __syncthreads();
    for (int i = tid; i < m; i += 256) atomicAdd(&cnt[sdst[base + i]], 1);
    __syncthreads();
    int v = cnt[tid];
    s[tid] = v;
    __syncthreads();
    for (int off = 1; off < 256; off <<= 1) {
        int t = (tid >= off) ? s[tid - off] : 0;
        __syncthreads();
        s[tid] += t;
        __syncthreads();
    }
    int excl = s[tid] - v;
    pos[tid] = excl;
    int node = bkt * BKT_NODES + tid;
    if (node < N) {
        rp[node] = base + excl;
        dinv[node] = rsqrtf((float)(v + 1));  // +1: self-loop
    }
    __syncthreads();
    for (int i = tid; i < m; i += 256) {
        int r = atomicAdd(&pos[sdst[base + i]], 1);
        col[base + r] = ssrc[base + i];
    }
    if (bkt == 0 && tid == 0) rp[N] = E;
}

// ---------------- LayerNorm (+ pre-scale by dinv), fp16 output ----------------

__global__ __launch_bounds__(256) void k_ln(const float* __restrict__ x,
                                            const float* __restrict__ w,
                                            const float* __restrict__ bb,
                                            const float* __restrict__ dinv,
                                            __half2* __restrict__ u, int N) {
    int row = (blockIdx.x * 256 + threadIdx.x) >> 6;
    int lane = threadIdx.x & 63;
    if (row >= N) return;
    float2 v = *(const float2*)(x + (size_t)row * DIM + lane * 2);
    float s = v.x + v.y;
#pragma unroll
    for (int o = 32; o; o >>= 1) s += __shfl_xor(s, o, 64);
    float mu = s * (1.0f / 128.0f);
    float dx0 = v.x - mu, dx1 = v.y - mu;
    float ss = dx0 * dx0 + dx1 * dx1;
#pragma unroll
    for (int o = 32; o; o >>= 1) ss += __shfl_xor(ss, o, 64);
    float rs = rsqrtf(ss * (1.0f / 128.0f) + 1e-5f);
    float2 wv = *(const float2*)(w + lane * 2);
    float2 bv = *(const float2*)(bb + lane * 2);
    float di = dinv[row];
    float o0 = (dx0 * rs * wv.x + bv.x) * di;
    float o1 = (dx1 * rs * wv.y + bv.y) * di;
    u[(size_t)row * 64 + lane] = __floats2half2_rn(o0, o1);
}

// ---------------- propagate: Y[i] = scale * (X[i] + sum_{e in(i)} X[src]) ----------------
// 16 nodes per block; each 16-lane group owns one node (q = feature slice of 8 halves).
// 8-deep edge unroll -> up to 32 independent row-gathers in flight per wave.

__global__ __launch_bounds__(256) void k_prop(const _Float16* __restrict__ X,
                                              _Float16* __restrict__ Y,
                                              const int* __restrict__ rp,
                                              const int* __restrict__ col,
                                              const float* __restrict__ dinv, int N, int squared) {
    int tid = threadIdx.x;
    int node = blockIdx.x * 16 + (tid >> 4);
    int q = tid & 15;
    if (node >= N) return;
    const _Float16* xq = X + q * 8;
    half8 selfv = *(const half8*)(xq + (size_t)node * DIM);
    int e0 = rp[node], e1 = rp[node + 1];
    float acc[8];
#pragma unroll
    for (int f = 0; f < 8; f++) acc[f] = 0.f;
    int e = e0;
    for (; e + 7 < e1; e += 8) {
        int s0 = col[e + 0], s1 = col[e + 1], s2 = col[e + 2], s3 = col[e + 3];
        int s4 = col[e + 4], s5 = col[e + 5], s6 = col[e + 6], s7 = col[e + 7];
        half8 g0 = *(const half8*)(xq + (size_t)s0 * DIM);
        half8 g1 = *(const half8*)(xq + (size_t)s1 * DIM);
        half8 g2 = *(const half8*)(xq + (size_t)s2 * DIM);
        half8 g3 = *(const half8*)(xq + (size_t)s3 * DIM);
        half8 g4 = *(const half8*)(xq + (size_t)s4 * DIM);
        half8 g5 = *(const half8*)(xq + (size_t)s5 * DIM);
        half8 g6 = *(const half8*)(xq + (size_t)s6 * DIM);
        half8 g7 = *(const half8*)(xq + (size_t)s7 * DIM);
#pragma unroll
        for (int f = 0; f < 8; f++)
            acc[f] += (((float)g0[f] + (float)g1[f]) + ((float)g2[f] + (float)g3[f])) +
                      (((float)g4[f] + (float)g5[f]) + ((float)g6[f] + (float)g7[f]));
    }
    for (; e + 1 < e1; e += 2) {
        int s0 = col[e], s1 = col[e + 1];
        half8 g0 = *(const half8*)(xq + (size_t)s0 * DIM);
        half8 g1 = *(const half8*)(xq + (size_t)s1 * DIM);
#pragma unroll
        for (int f = 0; f < 8; f++) acc[f] += (float)g0[f] + (float)g1[f];
    }
    if (e < e1) {
        int s = col[e];
        half8 g = *(const half8*)(xq + (size_t)s * DIM);
#pragma unroll
        for (int f = 0; f < 8; f++) acc[f] += (float)g[f];
    }
    float di = dinv[node];
    float sc = squared ? di * di : di;
    half8 o;
#pragma unroll
    for (int f = 0; f < 8; f++) o[f] = (_Float16)(((float)selfv[f] + acc[f]) * sc);
    *(half8*)(Y + (size_t)node * DIM + q * 8) = o;
}

// ---------------- W fragment pre-pack + MFMA tall-skinny matmul ----------------
// pack[((tile*4+ks)*64 + lane)*8 + j] = (fp16) W[tile*16 + (lane&15)][ks*32 + 8*(lane>>4) + j]

__global__ __launch_bounds__(256) void k_packW(const float* __restrict__ W,
                                               _Float16* __restrict__ pack) {
    int t = blockIdx.x * 256 + threadIdx.x;  // 0..2047
    if (t >= 2048) return;
    int lane = t & 63, ks = (t >> 6) & 3, tile = t >> 8;
    int wrow = tile * 16 + (lane & 15);
    int wcol = ks * 32 + 8 * (lane >> 4);
    float4 w0 = *(const float4*)(W + wrow * DIM + wcol);
    float4 w1 = *(const float4*)(W + wrow * DIM + wcol + 4);
    _Float16* dst = pack + (size_t)t * 8;
    dst[0] = (_Float16)w0.x; dst[1] = (_Float16)w0.y;
    dst[2] = (_Float16)w0.z; dst[3] = (_Float16)w0.w;
    dst[4] = (_Float16)w1.x; dst[5] = (_Float16)w1.y;
    dst[6] = (_Float16)w1.z; dst[7] = (_Float16)w1.w;
}

// 4 waves/block, 16 rows per wave, 64 rows/block. A from global, B from pack (L2-hot).
__global__ __launch_bounds__(256) void k_mm(const _Float16* __restrict__ Z,
                                            const _Float16* __restrict__ pack,
                                            const float* __restrict__ bias,
                                            float* __restrict__ out, int N) {
    int wave = threadIdx.x >> 6;
    int lane = threadIdx.x & 63;
    int rB = blockIdx.x * 64 + wave * 16;
    int r = rB + (lane & 15);
    bool rok = (r < N);
    half8 a[4];
    if (rok) {
        const _Float16* zr = Z + (size_t)r * DIM + 8 * (lane >> 4);
#pragma unroll
        for (int ks = 0; ks < 4; ks++) a[ks] = *(const half8*)(zr + ks * 32);
    } else {
#pragma unroll
        for (int ks = 0; ks < 4; ks++)
#pragma unroll
            for (int j = 0; j < 8; j++) a[ks][j] = (_Float16)0;
    }
    int row0 = rB + (lane >> 4) * 4;
#pragma unroll
    for (int tile = 0; tile < 8; tile++) {
        f32x4 d = {0.f, 0.f, 0.f, 0.f};
#pragma unroll
        for (int ks = 0; ks < 4; ks++) {
            half8 bf = *(const half8*)(pack + ((size_t)((tile * 4 + ks) * 64 + lane)) * 8);
            d = __builtin_amdgcn_mfma_f32_16x16x32_f16(a[ks], bf, d, 0, 0, 0);
        }
        int c = tile * 16 + (lane & 15);
        float bv = bias[c];
#pragma unroll
        for (int j = 0; j < 4; j++) {
            int rr = row0 + j;
            if (rr < N) out[(size_t)rr * DIM + c] = d[j] + bv;
        }
    }
}

// ---------------- launch ----------------

extern "C" void kernel_launch(void* const* d_in, const int* in_sizes, int n_in, void* d_out,
                              int out_size, void* d_ws, size_t ws_size, hipStream_t stream) {
    const float* x = (const float*)d_in[0];
    const int* ei = (const int*)d_in[1];
    const float* ln_w = (const float*)d_in[2];
    const float* ln_b = (const float*)d_in[3];
    const float* W = (const float*)d_in[4];
    const float* b = (const float*)d_in[5];
    float* out = (float*)d_out;

    int N = in_sizes[0] / DIM;
    int E = in_sizes[1] / 2;

    int NBUK = (N + BKT_NODES - 1) / BKT_NODES;  // 391
    int NBLK = (E + CHUNK - 1) / CHUNK;          // 196
    int M = NBUK * NBLK;                         // 76,636
    int gScan = (M + 255) / 256;                 // 300 (<= 1024)

    // workspace carve-up (all 256B-aligned)
    char* p = (char*)d_ws;
    auto carve = [&](size_t bytes) {
        void* r = (void*)p;
        p += (bytes + 255) & ~(size_t)255;
        return r;
    };
    __half* u0 = (__half*)carve((size_t)N * DIM * 2);      // 25.6 MB ping
    __half* u1 = (__half*)carve((size_t)N * DIM * 2);      // 25.6 MB pong
    _Float16* pack = (_Float16*)carve(DIM * DIM * 2);      // 32 KB packed W fragments
    int* H = (int*)carve((size_t)M * 4);                   // 306 KB bucket histograms
    float* dinv = (float*)carve((size_t)N * 4);
    int* rp = (int*)carve((size_t)(N + 1) * 4);
    int* tmp = (int*)carve((size_t)(N > M ? N : M) * 4);
    int* bsum = (int*)carve(1024 * 4);
    int* col = (int*)carve((size_t)E * 4);                 // 6.4 MB

    // sorted-edge arrays overlay u1 (dead until prop hop 1 writes it)
    int* ssrc = (int*)u1;                                  // E ints = 6.4 MB
    unsigned char* sdst = (unsigned char*)u1 + ((size_t)E * 4 + 255 & ~(size_t)255);  // E bytes

    int gW = (N + 3) / 4;     // wave-per-row kernels: 25000
    int gP = (N + 15) / 16;   // prop: 16 nodes/block: 6250
    int gM = (N + 63) / 64;   // matmul row blocks: 1563

    k_s1_hist<<<NBLK, 256, 0, stream>>>(ei, H, E, NBUK, NBLK);
    k_scanA<<<gScan, 256, 0, stream>>>(H, tmp, bsum, M);
    k_scanB<<<1, 1024, 0, stream>>>(bsum, gScan);
    k_scanE<<<gScan, 256, 0, stream>>>(H, tmp, bsum, M);
    k_s3_scatter<<<NBLK, 256, 0, stream>>>(ei, H, ssrc, sdst, E, NBUK, NBLK);
    k_s4_build<<<NBUK, 256, 0, stream>>>(H, ssrc, sdst, rp, dinv, col, N, E, NBUK, NBLK);
    k_packW<<<8, 256, 0, stream>>>(W, pack);
    k_ln<<<gW, 256, 0, stream>>>(x, ln_w, ln_b, dinv, (__half2*)u0, N);
    // hop 1: u0 -> u1 (pre-scaled by dinv^2)   (clobbers ssrc/sdst — dead here)
    k_prop<<<gP, 256, 0, stream>>>((const _Float16*)u0, (_Float16*)u1, rp, col, dinv, N, 1);
    // hop 2: u1 -> u0 (scaled by dinv)
    k_prop<<<gP, 256, 0, stream>>>((const _Float16*)u1, (_Float16*)u0, rp, col, dinv, N, 0);
    // out = z2 @ W^T + b  (MFMA fp16, fp32 accumulate)
    k_mm<<<gM, 256, 0, stream>>>((const _Float16*)u0, pack, b, out, N);
}

// Round 9
// 219.533 us; speedup vs baseline: 2.8514x; 1.0280x over previous
//
#include <hip/hip_runtime.h>
#include <hip/hip_fp16.h>

#define DIM 128
#define BKT_SHIFT 8    // 256 nodes per bucket
#define BKT_NODES 256
#define CHUNK 4096     // edges per S1/S3 block (1024-thread blocks)
#define MAXBUK 1024    // LDS histogram capacity (NBUK = ceil(N/256) must be <= this)
#define ZROW 136       // LDS z-tile row stride in halves (+8 pad: bank-spread)

typedef _Float16 half8 __attribute__((ext_vector_type(8)));
typedef float f32x4 __attribute__((ext_vector_type(4)));

// ---------------- S1: per-chunk bucket histogram (LDS atomics only) ----------------

__global__ __launch_bounds__(1024) void k_s1_hist(const int* __restrict__ ei, int* __restrict__ H,
                                                  int E, int NBUK, int NBLK) {
    __shared__ int hist[MAXBUK];
    int b = blockIdx.x, tid = threadIdx.x;
    for (int i = tid; i < NBUK; i += 1024) hist[i] = 0;
    __syncthreads();
    int e0 = b * CHUNK, e1 = min(e0 + CHUNK, E);
    for (int e = e0 + tid; e < e1; e += 1024) {
        int dst = ei[E + e];
        atomicAdd(&hist[dst >> BKT_SHIFT], 1);
    }
    __syncthreads();
    for (int k = tid; k < NBUK; k += 1024) H[(size_t)k * NBLK + b] = hist[k];
}

// ---------------- S2: flat exclusive scan of H (bucket-major) ----------------

__global__ __launch_bounds__(256) void k_scanA(const int* __restrict__ in, int* __restrict__ tmp,
                                               int* __restrict__ bsum, int n) {
    __shared__ int s[256];
    int tid = threadIdx.x;
    int i = blockIdx.x * 256 + tid;
    int v = (i < n) ? in[i] : 0;
    s[tid] = v;
    __syncthreads();
    for (int off = 1; off < 256; off <<= 1) {
        int t = (tid >= off) ? s[tid - off] : 0;
        __syncthreads();
        s[tid] += t;
        __syncthreads();
    }
    if (i < n) tmp[i] = s[tid];  // inclusive within block
    if (tid == 255) bsum[blockIdx.x] = s[255];
}

__global__ __launch_bounds__(1024) void k_scanB(int* __restrict__ bsum, int nb) {
    __shared__ int s[1024];
    int tid = threadIdx.x;
    int v = (tid < nb) ? bsum[tid] : 0;
    s[tid] = v;
    __syncthreads();
    for (int off = 1; off < 1024; off <<= 1) {
        int t = (tid >= off) ? s[tid - off] : 0;
        __syncthreads();
        s[tid] += t;
        __syncthreads();
    }
    if (tid < nb) bsum[tid] = s[tid] - v;  // exclusive block offsets
}

// in-place: H[i] = exclusive_global(i) = bsum[blk] + tmp[i] - H[i]
__global__ __launch_bounds__(256) void k_scanE(int* __restrict__ H, const int* __restrict__ tmp,
                                               const int* __restrict__ bsum, int n) {
    int i = blockIdx.x * 256 + threadIdx.x;
    if (i < n) H[i] = bsum[blockIdx.x] + tmp[i] - H[i];
}

// ---------------- S3: scatter edges into bucket-sorted order ----------------

__global__ __launch_bounds__(1024) void k_s3_scatter(const int* __restrict__ ei,
                                                     const int* __restrict__ H,
                                                     int* __restrict__ ssrc,
                                                     unsigned char* __restrict__ sdst, int E,
                                                     int NBUK, int NBLK) {
    __shared__ int off[MAXBUK];
    int b = blockIdx.x, tid = threadIdx.x;
    for (int k = tid; k < NBUK; k += 1024) off[k] = H[(size_t)k * NBLK + b];
    __syncthreads();
    int e0 = b * CHUNK, e1 = min(e0 + CHUNK, E);
    for (int e = e0 + tid; e < e1; e += 1024) {
        int src = ei[e];
        int dst = ei[E + e];
        int p = atomicAdd(&off[dst >> BKT_SHIFT], 1);
        ssrc[p] = src;
        sdst[p] = (unsigned char)(dst & (BKT_NODES - 1));
    }
}

// ---------------- S4: per-bucket CSR build + deg/dinv/rp ----------------

__global__ __launch_bounds__(256) void k_s4_build(const int* __restrict__ H,
                                                  const int* __restrict__ ssrc,
                                                  const unsigned char* __restrict__ sdst,
                                                  int* __restrict__ rp, float* __restrict__ dinv,
                                                  int* __restrict__ col, int N, int E, int NBUK,
                                                  int NBLK) {
    __shared__ int cnt[BKT_NODES];
    __shared__ int pos[BKT_NODES];
    __shared__ int s[BKT_NODES];
    int bkt = blockIdx.x, tid = threadIdx.x;
    int base = H[(size_t)bkt * NBLK];
    int endv = (bkt + 1 < NBUK) ? H[(size_t)(bkt + 1) * NBLK] : E;
    int m = endv - base;
    cnt[tid] = 0;
    __syncthreads();
    for (int i = tid; i < m; i += 256) atomicAdd(&cnt[sdst[base + i]], 1);
    __syncthreads();
    int v = cnt[tid];
    s[tid] = v;
    __syncthreads();
    for (int off = 1; off < 256; off <<= 1) {
        int t = (tid >= off) ? s[tid - off] : 0;
        __syncthreads();
        s[tid] += t;
        __syncthreads();
    }
    int excl = s[tid] - v;
    pos[tid] = excl;
    int node = bkt * BKT_NODES + tid;
    if (node < N) {
        rp[node] = base + excl;
        dinv[node] = rsqrtf((float)(v + 1));  // +1: self-loop
    }
    __syncthreads();
    for (int i = tid; i < m; i += 256) {
        int r = atomicAdd(&pos[sdst[base + i]], 1);
        col[base + r] = ssrc[base + i];
    }
    if (bkt == 0 && tid == 0) rp[N] = E;
}

// ---------------- LayerNorm (+ pre-scale by dinv), fp16 output ----------------

__global__ __launch_bounds__(256) void k_ln(const float* __restrict__ x,
                                            const float* __restrict__ w,
                                            const float* __restrict__ bb,
                                            const float* __restrict__ dinv,
                                            __half2* __restrict__ u, int N) {
    int row = (blockIdx.x * 256 + threadIdx.x) >> 6;
    int lane = threadIdx.x & 63;
    if (row >= N) return;
    float2 v = *(const float2*)(x + (size_t)row * DIM + lane * 2);
    float s = v.x + v.y;
#pragma unroll
    for (int o = 32; o; o >>= 1) s += __shfl_xor(s, o, 64);
    float mu = s * (1.0f / 128.0f);
    float dx0 = v.x - mu, dx1 = v.y - mu;
    float ss = dx0 * dx0 + dx1 * dx1;
#pragma unroll
    for (int o = 32; o; o >>= 1) ss += __shfl_xor(ss, o, 64);
    float rs = rsqrtf(ss * (1.0f / 128.0f) + 1e-5f);
    float2 wv = *(const float2*)(w + lane * 2);
    float2 bv = *(const float2*)(bb + lane * 2);
    float di = dinv[row];
    float o0 = (dx0 * rs * wv.x + bv.x) * di;
    float o1 = (dx1 * rs * wv.y + bv.y) * di;
    u[(size_t)row * 64 + lane] = __floats2half2_rn(o0, o1);
}

// ---------------- hop 1: Y[i] = dinv^2 * (X[i] + sum_{e in(i)} X[src]) ----------------
// 16 nodes per block; each 16-lane group owns one node (q = feature slice of 8 halves).

__global__ __launch_bounds__(256) void k_prop(const _Float16* __restrict__ X,
                                              _Float16* __restrict__ Y,
                                              const int* __restrict__ rp,
                                              const int* __restrict__ col,
                                              const float* __restrict__ dinv, int N) {
    int tid = threadIdx.x;
    int node = blockIdx.x * 16 + (tid >> 4);
    int q = tid & 15;
    if (node >= N) return;
    const _Float16* xq = X + q * 8;
    half8 selfv = *(const half8*)(xq + (size_t)node * DIM);
    int e0 = rp[node], e1 = rp[node + 1];
    float acc[8];
#pragma unroll
    for (int f = 0; f < 8; f++) acc[f] = 0.f;
    int e = e0;
    for (; e + 7 < e1; e += 8) {
        int s0 = col[e + 0], s1 = col[e + 1], s2 = col[e + 2], s3 = col[e + 3];
        int s4 = col[e + 4], s5 = col[e + 5], s6 = col[e + 6], s7 = col[e + 7];
        half8 g0 = *(const half8*)(xq + (size_t)s0 * DIM);
        half8 g1 = *(const half8*)(xq + (size_t)s1 * DIM);
        half8 g2 = *(const half8*)(xq + (size_t)s2 * DIM);
        half8 g3 = *(const half8*)(xq + (size_t)s3 * DIM);
        half8 g4 = *(const half8*)(xq + (size_t)s4 * DIM);
        half8 g5 = *(const half8*)(xq + (size_t)s5 * DIM);
        half8 g6 = *(const half8*)(xq + (size_t)s6 * DIM);
        half8 g7 = *(const half8*)(xq + (size_t)s7 * DIM);
#pragma unroll
        for (int f = 0; f < 8; f++)
            acc[f] += (((float)g0[f] + (float)g1[f]) + ((float)g2[f] + (float)g3[f])) +
                      (((float)g4[f] + (float)g5[f]) + ((float)g6[f] + (float)g7[f]));
    }
    for (; e + 1 < e1; e += 2) {
        int s0 = col[e], s1 = col[e + 1];
        half8 g0 = *(const half8*)(xq + (size_t)s0 * DIM);
        half8 g1 = *(const half8*)(xq + (size_t)s1 * DIM);
#pragma unroll
        for (int f = 0; f < 8; f++) acc[f] += (float)g0[f] + (float)g1[f];
    }
    if (e < e1) {
        int s = col[e];
        half8 g = *(const half8*)(xq + (size_t)s * DIM);
#pragma unroll
        for (int f = 0; f < 8; f++) acc[f] += (float)g[f];
    }
    float di = dinv[node];
    float sc = di * di;
    half8 o;
#pragma unroll
    for (int f = 0; f < 8; f++) o[f] = (_Float16)(((float)selfv[f] + acc[f]) * sc);
    *(half8*)(Y + (size_t)node * DIM + q * 8) = o;
}

// ---------------- W fragment pre-pack ----------------
// pack[((tile*4+ks)*64 + lane)*8 + j] = (fp16) W[tile*16 + (lane&15)][ks*32 + 8*(lane>>4) + j]

__global__ __launch_bounds__(256) void k_packW(const float* __restrict__ W,
                                               _Float16* __restrict__ pack) {
    int t = blockIdx.x * 256 + threadIdx.x;  // 0..2047
    if (t >= 2048) return;
    int lane = t & 63, ks = (t >> 6) & 3, tile = t >> 8;
    int wrow = tile * 16 + (lane & 15);
    int wcol = ks * 32 + 8 * (lane >> 4);
    float4 w0 = *(const float4*)(W + wrow * DIM + wcol);
    float4 w1 = *(const float4*)(W + wrow * DIM + wcol + 4);
    _Float16* dst = pack + (size_t)t * 8;
    dst[0] = (_Float16)w0.x; dst[1] = (_Float16)w0.y;
    dst[2] = (_Float16)w0.z; dst[3] = (_Float16)w0.w;
    dst[4] = (_Float16)w1.x; dst[5] = (_Float16)w1.y;
    dst[6] = (_Float16)w1.z; dst[7] = (_Float16)w1.w;
}

// ---------------- fused hop 2 + matmul ----------------
// 64 nodes per block. Phase 1: 16 groups of 16 lanes gather 4 nodes each into LDS
// (z2 = dinv*(self + sum), fp16, padded stride). Phase 2: 4 waves MFMA from LDS,
// write out = z2 @ W^T + b directly. Saves the z2 global write + re-read.

__global__ __launch_bounds__(256) void k_prop_mm(const _Float16* __restrict__ X,
                                                 const int* __restrict__ rp,
                                                 const int* __restrict__ col,
                                                 const float* __restrict__ dinv,
                                                 const _Float16* __restrict__ pack,
                                                 const float* __restrict__ bias,
                                                 float* __restrict__ out, int N) {
    __shared__ _Float16 Z[64 * ZROW];
    int tid = threadIdx.x;
    int rB = blockIdx.x * 64;
    int g = tid >> 4;  // group 0..15
    int q = tid & 15;  // feature slice
    const _Float16* xq = X + q * 8;
#pragma unroll
    for (int k = 0; k < 4; k++) {
        int lrow = g * 4 + k;
        int node = rB + lrow;
        half8 o;
        if (node < N) {
            half8 selfv = *(const half8*)(xq + (size_t)node * DIM);
            int e0 = rp[node], e1 = rp[node + 1];
            float acc[8];
#pragma unroll
            for (int f = 0; f < 8; f++) acc[f] = 0.f;
            int e = e0;
            for (; e + 7 < e1; e += 8) {
                int s0 = col[e + 0], s1 = col[e + 1], s2 = col[e + 2], s3 = col[e + 3];
                int s4 = col[e + 4], s5 = col[e + 5], s6 = col[e + 6], s7 = col[e + 7];
                half8 g0 = *(const half8*)(xq + (size_t)s0 * DIM);
                half8 g1 = *(const half8*)(xq + (size_t)s1 * DIM);
                half8 g2 = *(const half8*)(xq + (size_t)s2 * DIM);
                half8 g3 = *(const half8*)(xq + (size_t)s3 * DIM);
                half8 g4 = *(const half8*)(xq + (size_t)s4 * DIM);
                half8 g5 = *(const half8*)(xq + (size_t)s5 * DIM);
                half8 g6 = *(const half8*)(xq + (size_t)s6 * DIM);
                half8 g7 = *(const half8*)(xq + (size_t)s7 * DIM);
#pragma unroll
                for (int f = 0; f < 8; f++)
                    acc[f] += (((float)g0[f] + (float)g1[f]) + ((float)g2[f] + (float)g3[f])) +
                              (((float)g4[f] + (float)g5[f]) + ((float)g6[f] + (float)g7[f]));
            }
            for (; e + 1 < e1; e += 2) {
                int s0 = col[e], s1 = col[e + 1];
                half8 g0 = *(const half8*)(xq + (size_t)s0 * DIM);
                half8 g1 = *(const half8*)(xq + (size_t)s1 * DIM);
#pragma unroll
                for (int f = 0; f < 8; f++) acc[f] += (float)g0[f] + (float)g1[f];
            }
            if (e < e1) {
                int s = col[e];
                half8 gg = *(const half8*)(xq + (size_t)s * DIM);
#pragma unroll
                for (int f = 0; f < 8; f++) acc[f] += (float)gg[f];
            }
            float sc = dinv[node];
#pragma unroll
            for (int f = 0; f < 8; f++) o[f] = (_Float16)(((float)selfv[f] + acc[f]) * sc);
        } else {
#pragma unroll
            for (int f = 0; f < 8; f++) o[f] = (_Float16)0;
        }
        *(half8*)(&Z[lrow * ZROW + q * 8]) = o;
    }
    __syncthreads();
    // Phase 2: MFMA. Wave w handles local rows w*16..w*16+15.
    int wave = tid >> 6;
    int lane = tid & 63;
    int rw = wave * 16;
    half8 a[4];
#pragma unroll
    for (int ks = 0; ks < 4; ks++)
        a[ks] = *(const half8*)(&Z[(rw + (lane & 15)) * ZROW + ks * 32 + (lane >> 4) * 8]);
    int row0 = rB + rw + (lane >> 4) * 4;
#pragma unroll
    for (int tile = 0; tile < 8; tile++) {
        f32x4 d = {0.f, 0.f, 0.f, 0.f};
#pragma unroll
        for (int ks = 0; ks < 4; ks++) {
            half8 bf = *(const half8*)(pack + ((size_t)((tile * 4 + ks) * 64 + lane)) * 8);
            d = __builtin_amdgcn_mfma_f32_16x16x32_f16(a[ks], bf, d, 0, 0, 0);
        }
        int c = tile * 16 + (lane & 15);
        float bv = bias[c];
#pragma unroll
        for (int j = 0; j < 4; j++) {
            int rr = row0 + j;
            if (rr < N) out[(size_t)rr * DIM + c] = d[j] + bv;
        }
    }
}

// ---------------- launch ----------------

extern "C" void kernel_launch(void* const* d_in, const int* in_sizes, int n_in, void* d_out,
                              int out_size, void* d_ws, size_t ws_size, hipStream_t stream) {
    const float* x = (const float*)d_in[0];
    const int* ei = (const int*)d_in[1];
    const float* ln_w = (const float*)d_in[2];
    const float* ln_b = (const float*)d_in[3];
    const float* W = (const float*)d_in[4];
    const float* b = (const float*)d_in[5];
    float* out = (float*)d_out;

    int N = in_sizes[0] / DIM;
    int E = in_sizes[1] / 2;

    int NBUK = (N + BKT_NODES - 1) / BKT_NODES;  // 391
    int NBLK = (E + CHUNK - 1) / CHUNK;          // 391
    int M = NBUK * NBLK;                         // 152,881
    int gScan = (M + 255) / 256;                 // 598 (<= 1024)

    // workspace carve-up (all 256B-aligned)
    char* p = (char*)d_ws;
    auto carve = [&](size_t bytes) {
        void* r = (void*)p;
        p += (bytes + 255) & ~(size_t)255;
        return r;
    };
    __half* u0 = (__half*)carve((size_t)N * DIM * 2);      // 25.6 MB ping
    __half* u1 = (__half*)carve((size_t)N * DIM * 2);      // 25.6 MB pong
    _Float16* pack = (_Float16*)carve(DIM * DIM * 2);      // 32 KB packed W fragments
    int* H = (int*)carve((size_t)M * 4);                   // 600 KB bucket histograms
    float* dinv = (float*)carve((size_t)N * 4);
    int* rp = (int*)carve((size_t)(N + 1) * 4);
    int* tmp = (int*)carve((size_t)(N > M ? N : M) * 4);
    int* bsum = (int*)carve(1024 * 4);
    int* col = (int*)carve((size_t)E * 4);                 // 6.4 MB

    // sorted-edge arrays overlay u1 (dead until prop hop 1 writes it)
    int* ssrc = (int*)u1;                                  // E ints = 6.4 MB
    unsigned char* sdst = (unsigned char*)u1 + ((size_t)E * 4 + 255 & ~(size_t)255);  // E bytes

    int gW = (N + 3) / 4;     // wave-per-row kernels: 25000
    int gP = (N + 15) / 16;   // prop hop1: 16 nodes/block: 6250
    int gM = (N + 63) / 64;   // fused hop2+matmul: 64 rows/block: 1563

    k_s1_hist<<<NBLK, 1024, 0, stream>>>(ei, H, E, NBUK, NBLK);
    k_scanA<<<gScan, 256, 0, stream>>>(H, tmp, bsum, M);
    k_scanB<<<1, 1024, 0, stream>>>(bsum, gScan);
    k_scanE<<<gScan, 256, 0, stream>>>(H, tmp, bsum, M);
    k_s3_scatter<<<NBLK, 1024, 0, stream>>>(ei, H, ssrc, sdst, E, NBUK, NBLK);
    k_s4_build<<<NBUK, 256, 0, stream>>>(H, ssrc, sdst, rp, dinv, col, N, E, NBUK, NBLK);
    k_packW<<<8, 256, 0, stream>>>(W, pack);
    k_ln<<<gW, 256, 0, stream>>>(x, ln_w, ln_b, dinv, (__half2*)u0, N);
    // hop 1: u0 -> u1 (pre-scaled by dinv^2)   (clobbers ssrc/sdst — dead here)
    k_prop<<<gP, 256, 0, stream>>>((const _Float16*)u0, (_Float16*)u1, rp, col, dinv, N);
    // fused hop 2 + matmul: u1 -> out
    k_prop_mm<<<gM, 256, 0, stream>>>((const _Float16*)u1, rp, col, dinv, pack, b, out, N);
}